// Round 9
// baseline (322.571 us; speedup 1.0000x reference)
//
#include <hip/hip_runtime.h>

// GCN: 2-layer GraphConv, N=100000, E=1600000, 128 -> 128 -> 40 (fp32).
// Round 18: un-fuse (fused structure pins at 2.8 TB/s vs gather1's 3.83).
//   gather1:  R1-proven form (79.6us): 1 wave/node, 16-edge predicated
//             batches, uint4 row reads, writes aggb.
//   gemm12:   32 rows/block, 3125 blocks: At from aggb, weights from global,
//             GEMM1 split (row-tile, nt-half) over 4 waves, GEMM2 waves 0/2.
//   build:    BKSH=8 (391 buckets of 256 nodes): pass2 2x blocks; partition
//             512-thread (R4-validated); basescan feeds bases.
//   gather2:  unchanged.
constexpr int NN   = 100000;
constexpr int NE   = 1600000;
constexpr int INF  = 128;
constexpr int NC   = 40;

constexpr int BKSH = 8;                        // 256 nodes per bucket
constexpr int NBK  = (NN + 255) / 256;         // 391 buckets
constexpr int EPB  = 4096;                     // edges per partition block
constexpr int PBLK = (NE + EPB - 1) / EPB;     // 391
constexpr int CAP  = 8192;                     // pass2 LDS esrc capacity (32 KB)
constexpr int HB   = 391;                      // hist blocks in merged kernel

typedef __attribute__((ext_vector_type(8))) short short8;
typedef __attribute__((ext_vector_type(4))) float f32x4;

__device__ __forceinline__ float bflo(unsigned int u) { return __uint_as_float(u << 16); }
__device__ __forceinline__ float bfhi(unsigned int u) { return __uint_as_float(u & 0xffff0000u); }
__device__ __forceinline__ unsigned short f2bf(float f) {          // RNE
    unsigned int u = __float_as_uint(f);
    return (unsigned short)((u + 0x7fffu + ((u >> 16) & 1u)) >> 16);
}
__device__ __forceinline__ unsigned int pack2(float a, float b) {
    return (unsigned int)f2bf(a) | ((unsigned int)f2bf(b) << 16);
}

// blocks 0..HB-1: coarse dst-bucket AND src-bucket histograms (LDS aggregated).
// blocks HB..HB+6249: x (fp32) -> xh (bf16). +2 blocks: W1/W2 transpose->bf16.
__global__ __launch_bounds__(256) void histconv_kernel(const int* __restrict__ src,
                                                       const int* __restrict__ dst,
                                                       unsigned int* __restrict__ bcntD,
                                                       unsigned int* __restrict__ bcntS,
                                                       const float* __restrict__ x,
                                                       const float* __restrict__ W1,
                                                       const float* __restrict__ W2,
                                                       unsigned short* __restrict__ xh,
                                                       unsigned short* __restrict__ w1t,
                                                       unsigned short* __restrict__ w2t) {
    const int b = blockIdx.x;
    const int tid = threadIdx.x;
    if (b < HB) {
        __shared__ unsigned int hcD[NBK];
        __shared__ unsigned int hcS[NBK];
        for (int i = tid; i < NBK; i += 256) { hcD[i] = 0u; hcS[i] = 0u; }
        __syncthreads();
        int gid = b * 256 + tid;
        int stride = HB * 256;
        for (int e = gid; e < NE; e += stride) {
            atomicAdd(&hcD[dst[e] >> BKSH], 1u);
            atomicAdd(&hcS[src[e] >> BKSH], 1u);
        }
        __syncthreads();
        for (int i = tid; i < NBK; i += 256) {
            if (hcD[i]) atomicAdd(&bcntD[i], hcD[i]);
            if (hcS[i]) atomicAdd(&bcntS[i], hcS[i]);
        }
    } else if (b < HB + 6250) {
        int j = (b - HB) * 256 + tid;                // uint4 index, N*128/8 = 1.6M
        float4 v0 = ((const float4*)x)[2 * j];
        float4 v1 = ((const float4*)x)[2 * j + 1];
        uint4 o;
        o.x = pack2(v0.x, v0.y);
        o.y = pack2(v0.z, v0.w);
        o.z = pack2(v1.x, v1.y);
        o.w = pack2(v1.z, v1.w);
        ((uint4*)xh)[j] = o;
    } else if (b == HB + 6250) {
        for (int i = tid; i < 128 * 128; i += 256) {
            int k = i >> 7, n = i & 127;
            w1t[n * 128 + k] = f2bf(W1[i]);
        }
    } else {
        for (int i = tid; i < 48 * 128; i += 256) {
            int n = i >> 7, k = i & 127;
            w2t[i] = f2bf((n < NC) ? W2[k * NC + n] : 0.f);
        }
    }
}

// 1 block x 512: exclusive scans of the 391 bucket counts (dst and src sides).
__global__ __launch_bounds__(512) void basescan_kernel(const unsigned int* __restrict__ bcntD,
                                                       const unsigned int* __restrict__ bcntS,
                                                       int* __restrict__ baseD,
                                                       int* __restrict__ baseS) {
    __shared__ int sc[512];
    const int tid = threadIdx.x;
    int v = (tid < NBK) ? (int)bcntD[tid] : 0;
    sc[tid] = v;
    __syncthreads();
    for (int off = 1; off < 512; off <<= 1) {
        int t = (tid >= off) ? sc[tid - off] : 0;
        __syncthreads();
        sc[tid] += t;
        __syncthreads();
    }
    if (tid < NBK) baseD[tid] = sc[tid] - v;
    __syncthreads();
    v = (tid < NBK) ? (int)bcntS[tid] : 0;
    sc[tid] = v;
    __syncthreads();
    for (int off = 1; off < 512; off <<= 1) {
        int t = (tid >= off) ? sc[tid - off] : 0;
        __syncthreads();
        sc[tid] += t;
        __syncthreads();
    }
    if (tid < NBK) baseS[tid] = sc[tid] - v;
}

// dual partition, 512 threads: dst-records (src | dst_local<<17) into epartsD,
// src-records (uchar src_local) into epartsS. LDS-staged -> coalesced dumps.
// Bucket bases precomputed (basescan).
__global__ __launch_bounds__(512) void partition_kernel(const int* __restrict__ src,
                                                        const int* __restrict__ dst,
                                                        const int* __restrict__ baseD,
                                                        const int* __restrict__ baseS,
                                                        int* __restrict__ curD_g,
                                                        int* __restrict__ curS_g,
                                                        int* __restrict__ epartsD,
                                                        unsigned short* __restrict__ epartsS) {
    __shared__ int sc[512];
    __shared__ int cntD[NBK], gadjD[NBK], curD[NBK];
    __shared__ int cntS[NBK], gadjS[NBK], curS[NBK];
    __shared__ int stageD[EPB];
    __shared__ unsigned short stageS[EPB];
    __shared__ unsigned short bidD[EPB];
    __shared__ unsigned short bidS[EPB];
    const int tid = threadIdx.x;
    const int e0 = blockIdx.x * EPB;
    const int total = min(EPB, NE - e0);

    for (int i = tid; i < NBK; i += 512) { cntD[i] = 0; cntS[i] = 0; }
    __syncthreads();
    // phase A: count per bucket (both keys)
    for (int i = tid; i < total; i += 512) {
        atomicAdd(&cntD[dst[e0 + i] >> BKSH], 1);
        atomicAdd(&cntS[src[e0 + i] >> BKSH], 1);
    }
    __syncthreads();
    // exclusive scans of cntD, cntS; reserve global ranges
    {
        int v = (tid < NBK) ? cntD[tid] : 0;
        sc[tid] = v;
        __syncthreads();
        for (int off = 1; off < 512; off <<= 1) {
            int t = (tid >= off) ? sc[tid - off] : 0;
            __syncthreads();
            sc[tid] += t;
            __syncthreads();
        }
        if (tid < NBK) {
            int excl = sc[tid] - v;
            curD[tid] = excl;
            int g = (v > 0) ? atomicAdd(&curD_g[tid], v) : 0;   // zero-based
            gadjD[tid] = baseD[tid] + g - excl;
        }
        __syncthreads();
        v = (tid < NBK) ? cntS[tid] : 0;
        sc[tid] = v;
        __syncthreads();
        for (int off = 1; off < 512; off <<= 1) {
            int t = (tid >= off) ? sc[tid - off] : 0;
            __syncthreads();
            sc[tid] += t;
            __syncthreads();
        }
        if (tid < NBK) {
            int excl = sc[tid] - v;
            curS[tid] = excl;
            int g = (v > 0) ? atomicAdd(&curS_g[tid], v) : 0;
            gadjS[tid] = baseS[tid] + g - excl;
        }
    }
    __syncthreads();
    // phase B: re-read edges, stage grouped by bucket (both keys)
    for (int i = tid; i < total; i += 512) {
        int s = src[e0 + i];
        int d = dst[e0 + i];
        int bD = d >> BKSH;
        int offD = atomicAdd(&curD[bD], 1);
        stageD[offD] = s | ((d - (bD << BKSH)) << 17);
        bidD[offD] = (unsigned short)bD;
        int bS = s >> BKSH;
        int offS = atomicAdd(&curS[bS], 1);
        stageS[offS] = (unsigned short)(s - (bS << BKSH));
        bidS[offS] = (unsigned short)bS;
    }
    __syncthreads();
    // dumps: consecutive j within a bucket-run -> consecutive global addresses
    for (int j = tid; j < total; j += 512) {
        int b = bidD[j];
        epartsD[gadjD[b] + j] = stageD[j];
    }
    for (int j = tid; j < total; j += 512) {
        int b = bidS[j];
        epartsS[gadjS[b] + j] = stageS[j];
    }
}

// 391 blocks x 256: per 256-node bucket: dst CSR (hist+scan+LDS scatter ->
// row_ptr, dstn, esrc) AND src out-degree hist -> srcn.
__global__ __launch_bounds__(256) void pass2_kernel(const int* __restrict__ epartsD,
                                                    const unsigned short* __restrict__ epartsS,
                                                    const int* __restrict__ baseD,
                                                    const int* __restrict__ baseS_g,
                                                    const unsigned int* __restrict__ bcntD,
                                                    const unsigned int* __restrict__ bcntS,
                                                    int* __restrict__ row_ptr,
                                                    int* __restrict__ esrc,
                                                    float* __restrict__ srcn,
                                                    float* __restrict__ dstn) {
    __shared__ int hist[256];
    __shared__ int cur[256];
    __shared__ int histS[256];
    __shared__ int lesrc[CAP];
    const int tid = threadIdx.x;
    const int b = blockIdx.x;

    const int base  = baseD[b];
    const int cnt   = (int)bcntD[b];
    const int baseS = baseS_g[b];
    const int cntS  = (int)bcntS[b];
    const int n0 = b << BKSH;
    const int nloc = min(256, NN - n0);

    hist[tid] = 0;
    histS[tid] = 0;
    __syncthreads();
    for (int j = tid; j < cnt; j += 256)
        atomicAdd(&hist[epartsD[base + j] >> 17], 1);
    for (int j = tid; j < cntS; j += 256)
        atomicAdd(&histS[(int)epartsS[baseS + j]], 1);
    __syncthreads();
    int myc = hist[tid];
    int mycS = histS[tid];
    for (int off = 1; off < 256; off <<= 1) {
        int t = (tid >= off) ? hist[tid - off] : 0;
        __syncthreads();
        hist[tid] += t;
        __syncthreads();
    }
    int excl = hist[tid] - myc;
    cur[tid] = excl;
    if (tid < nloc) {
        int g = n0 + tid;
        row_ptr[g] = base + excl;
        dstn[g] = rsqrtf(fmaxf((float)myc, 1.0f));    // dst_norm (in-degree)
        srcn[g] = rsqrtf(fmaxf((float)mycS, 1.0f));   // src_norm (out-degree)
    }
    if (b == NBK - 1 && tid == 0) row_ptr[NN] = NE;
    __syncthreads();
    if (cnt <= CAP) {
        for (int j = tid; j < cnt; j += 256) {
            int rec = epartsD[base + j];
            int pos = atomicAdd(&cur[rec >> 17], 1);
            lesrc[pos] = rec & 0x1FFFF;
        }
        __syncthreads();
        for (int j = tid; j < cnt; j += 256) esrc[base + j] = lesrc[j];
    } else {
        for (int j = tid; j < cnt; j += 256) {
            int rec = epartsD[base + j];
            int pos = atomicAdd(&cur[rec >> 17], 1);
            esrc[base + pos] = rec & 0x1FFFF;
        }
    }
}

// one wave per node: aggb[node] = bf16( sum x_bf16[esrc[e]] * src_norm[esrc[e]] )
// Predicated 16-edge batches: quad group owns edge slot t*4+quad, l16 reads
// uint4 (8 bf16) of the 256 B row. OOB slots clamp to `beg`, norm 0.
// R1-proven: 79.6us @ 3.83 TB/s, 28 VGPR, no LDS.
__global__ __launch_bounds__(256) void gather1_kernel(const int* __restrict__ row_ptr,
                                                      const int* __restrict__ esrc,
                                                      const unsigned short* __restrict__ xh,
                                                      const float* __restrict__ src_norm,
                                                      unsigned short* __restrict__ aggb) {
    int node = (blockIdx.x * blockDim.x + threadIdx.x) >> 6;
    int lane = threadIdx.x & 63;
    if (node >= NN) return;
    int beg = __builtin_amdgcn_readfirstlane(row_ptr[node]);
    int end = __builtin_amdgcn_readfirstlane(row_ptr[node + 1]);
    const int quad = lane >> 4;       // edge-slot group 0..3
    const int l16  = lane & 15;       // uint4 index within 256 B row
    float acc0 = 0.f, acc1 = 0.f, acc2 = 0.f, acc3 = 0.f;
    float acc4 = 0.f, acc5 = 0.f, acc6 = 0.f, acc7 = 0.f;
    for (int e = beg; e < end; e += 16) {
        const int rem = end - e;
        int s[4];
#pragma unroll
        for (int t = 0; t < 4; ++t) {
            int slot = t * 4 + quad;
            int idx = (slot < rem) ? (e + slot) : beg;
            s[t] = esrc[idx];
        }
        float n[4];
        uint4 u[4];
#pragma unroll
        for (int t = 0; t < 4; ++t) {
            int slot = t * 4 + quad;
            n[t] = (slot < rem) ? src_norm[s[t]] : 0.f;
            u[t] = ((const uint4*)(xh + (size_t)s[t] * INF))[l16];
        }
#pragma unroll
        for (int t = 0; t < 4; ++t) {
            acc0 += bflo(u[t].x) * n[t];
            acc1 += bfhi(u[t].x) * n[t];
            acc2 += bflo(u[t].y) * n[t];
            acc3 += bfhi(u[t].y) * n[t];
            acc4 += bflo(u[t].z) * n[t];
            acc5 += bfhi(u[t].z) * n[t];
            acc6 += bflo(u[t].w) * n[t];
            acc7 += bfhi(u[t].w) * n[t];
        }
    }
    // reduce across the 4 quad groups (same l16)
    acc0 += __shfl_down(acc0, 32); acc1 += __shfl_down(acc1, 32);
    acc2 += __shfl_down(acc2, 32); acc3 += __shfl_down(acc3, 32);
    acc4 += __shfl_down(acc4, 32); acc5 += __shfl_down(acc5, 32);
    acc6 += __shfl_down(acc6, 32); acc7 += __shfl_down(acc7, 32);
    acc0 += __shfl_down(acc0, 16); acc1 += __shfl_down(acc1, 16);
    acc2 += __shfl_down(acc2, 16); acc3 += __shfl_down(acc3, 16);
    acc4 += __shfl_down(acc4, 16); acc5 += __shfl_down(acc5, 16);
    acc6 += __shfl_down(acc6, 16); acc7 += __shfl_down(acc7, 16);
    if (lane < 16) {
        uint4 o;
        o.x = pack2(acc0, acc1);
        o.y = pack2(acc2, acc3);
        o.z = pack2(acc4, acc5);
        o.w = pack2(acc6, acc7);
        ((uint4*)(aggb + (size_t)node * INF))[l16] = o;
    }
}

// MFMA GEMM1+GEMM2, 32 rows/block, 3125 blocks, 4 waves.
// At staged from aggb; B-frags straight from global w1t/w2t (L2-hot).
// GEMM1 split (row-tile, nt-half) = (wv>>1, wv&1); race-safe ordering:
// stage -> barrier -> all waves load A-frags -> barrier -> MFMA + h into At
// -> barrier -> GEMM2 (waves 0/2).
__global__ __launch_bounds__(256, 4) void gemm12_kernel(const unsigned short* __restrict__ aggb,
                                                        const unsigned short* __restrict__ w1t,
                                                        const unsigned short* __restrict__ w2t,
                                                        const float* __restrict__ b1,
                                                        const float* __restrict__ dstn,
                                                        const float* __restrict__ srcn,
                                                        unsigned short* __restrict__ hwb) {
    __shared__ unsigned short At[32 * 128];    // 8 KB: agg tile, then h tile
    __shared__ float dn[32], sn[32], b1l[128];
    const int tid  = threadIdx.x;
    const int r0   = blockIdx.x * 32;
    const int wv   = tid >> 6;
    const int lane = tid & 63;

    {   // stage agg tile (zero-pad rows >= NN): 512 uint4
        const uint4* g = (const uint4*)(aggb + (size_t)r0 * 128);
        uint4* s = (uint4*)At;
        for (int i = tid; i < 512; i += 256) {
            int row = i >> 4;
            uint4 v = make_uint4(0, 0, 0, 0);
            if (r0 + row < NN) v = g[i];
            s[i] = v;
        }
    }
    if (tid < 32) {
        int r = r0 + tid;
        dn[tid] = (r < NN) ? dstn[r] : 0.f;
        sn[tid] = (r < NN) ? srcn[r] : 0.f;
    }
    if (tid >= 64 && tid < 192) b1l[tid - 64] = b1[tid - 64];
    __syncthreads();

    const int lrow  = lane & 15;
    const int lquad = lane >> 4;
    const int rt    = wv >> 1;            // row-tile 0 (rows 0-15) / 1 (16-31)
    const int ntB   = (wv & 1) * 4;       // nt-half 0-3 / 4-7

    // ALL waves snapshot their A-frags to registers before ANY h write.
    short8 afrag[4];
#pragma unroll
    for (int ks = 0; ks < 4; ++ks)
        afrag[ks] = *(const short8*)&At[(rt * 16 + lrow) * 128 + ks * 32 + lquad * 8];
    __syncthreads();   // agg reads complete before h overwrites At

    float hreg[4][4];
#pragma unroll
    for (int nt2 = 0; nt2 < 4; ++nt2) {
        f32x4 acc = {0.f, 0.f, 0.f, 0.f};
#pragma unroll
        for (int ks = 0; ks < 4; ++ks) {
            short8 bfr = *(const short8*)&w1t[((ntB + nt2) * 16 + lrow) * 128 + ks * 32 + lquad * 8];
            acc = __builtin_amdgcn_mfma_f32_16x16x32_bf16(afrag[ks], bfr, acc, 0, 0, 0);
        }
#pragma unroll
        for (int i = 0; i < 4; ++i) hreg[nt2][i] = acc[i];
    }
#pragma unroll
    for (int nt2 = 0; nt2 < 4; ++nt2) {
        int col = (ntB + nt2) * 16 + lrow;
        float bb = b1l[col];
#pragma unroll
        for (int i = 0; i < 4; ++i) {
            int row = rt * 16 + lquad * 4 + i;
            At[row * 128 + col] = f2bf(fmaxf(hreg[nt2][i] * dn[row] + bb, 0.f));
        }
    }
    __syncthreads();   // cross-wave: GEMM2 reads h cols written by nt-half peer

    // ---- GEMM2 on waves 0/2 (row-tile wv>>1) ----
    if ((wv & 1) == 0) {
        short8 hf[4];
#pragma unroll
        for (int ks = 0; ks < 4; ++ks)
            hf[ks] = *(const short8*)&At[(rt * 16 + lrow) * 128 + ks * 32 + lquad * 8];
#pragma unroll
        for (int nt = 0; nt < 3; ++nt) {
            f32x4 acc = {0.f, 0.f, 0.f, 0.f};
#pragma unroll
            for (int ks = 0; ks < 4; ++ks) {
                short8 bfr = *(const short8*)&w2t[(nt * 16 + lrow) * 128 + ks * 32 + lquad * 8];
                acc = __builtin_amdgcn_mfma_f32_16x16x32_bf16(hf[ks], bfr, acc, 0, 0, 0);
            }
            int col = nt * 16 + lrow;
            if (col < NC) {
#pragma unroll
                for (int i = 0; i < 4; ++i) {
                    int row = rt * 16 + lquad * 4 + i;
                    int grow = r0 + row;
                    if (grow < NN)
                        hwb[(size_t)grow * NC + col] = f2bf(acc[i] * sn[row]);
                }
            }
        }
    }
}

// one wave per node. lane = g*10+j (g<6, j<10): 6 edge slots, each edge's
// 80 B row read by 10 lanes as uint2 (4 bf16). Predicated 18-edge batches
// (3 independent loads per lane in flight); invalid slots clamp to edge `beg`
// with multiplicative zero mask. fp32 acc; shfl reduce into lanes 0..9,
// which store float4 with fused *dstn + b2.
__global__ __launch_bounds__(256) void gather2_kernel(const int* __restrict__ row_ptr,
                                                      const int* __restrict__ esrc,
                                                      const unsigned short* __restrict__ hwb,
                                                      const float* __restrict__ dst_norm,
                                                      const float* __restrict__ b2,
                                                      float* __restrict__ out) {
    int node = (blockIdx.x * blockDim.x + threadIdx.x) >> 6;
    int lane = threadIdx.x & 63;
    if (node >= NN) return;
    int beg = __builtin_amdgcn_readfirstlane(row_ptr[node]);
    int end = __builtin_amdgcn_readfirstlane(row_ptr[node + 1]);
    const int g = lane / 10;          // edge slot 0..5 (g==6: lanes 60-63 masked)
    const int j = lane - g * 10;      // uint2 index within 80 B row
    const bool active = (g < 6);
    float4 acc = make_float4(0.f, 0.f, 0.f, 0.f);
    for (int e = beg; e < end; e += 18) {
        const int rem = end - e;
        int s[3];
        float m[3];
#pragma unroll
        for (int q = 0; q < 3; ++q) {
            int slot = q * 6 + g;
            bool v = active && (slot < rem);
            int idx = v ? (e + slot) : beg;
            s[q] = esrc[idx];
            m[q] = v ? 1.f : 0.f;
        }
        uint2 u[3];
#pragma unroll
        for (int q = 0; q < 3; ++q)
            u[q] = ((const uint2*)(hwb + (size_t)s[q] * NC))[j];
#pragma unroll
        for (int q = 0; q < 3; ++q) {
            acc.x += bflo(u[q].x) * m[q];
            acc.y += bfhi(u[q].x) * m[q];
            acc.z += bflo(u[q].y) * m[q];
            acc.w += bfhi(u[q].y) * m[q];
        }
    }
    float4 tot = acc;
#pragma unroll
    for (int k = 1; k < 6; ++k) {
        tot.x += __shfl(acc.x, j + 10 * k);
        tot.y += __shfl(acc.y, j + 10 * k);
        tot.z += __shfl(acc.z, j + 10 * k);
        tot.w += __shfl(acc.w, j + 10 * k);
    }
    if (lane < 10) {
        float dnv = dst_norm[node];
        float4 bb = ((const float4*)b2)[j];
        float4 o;
        o.x = tot.x * dnv + bb.x;
        o.y = tot.y * dnv + bb.y;
        o.z = tot.z * dnv + bb.z;
        o.w = tot.w * dnv + bb.w;
        ((float4*)(out + (size_t)node * NC))[j] = o;
    }
}

extern "C" void kernel_launch(void* const* d_in, const int* in_sizes, int n_in,
                              void* d_out, int out_size, void* d_ws, size_t ws_size,
                              hipStream_t stream) {
    const float* x   = (const float*)d_in[0];
    const float* W1  = (const float*)d_in[1];
    const float* b1  = (const float*)d_in[2];
    const float* W2  = (const float*)d_in[3];
    const float* b2  = (const float*)d_in[4];
    const int*   src = (const int*)d_in[5];
    const int*   dst = (const int*)d_in[6];
    float* out = (float*)d_out;

    // workspace (4B units):
    // srcn[NN] | bcntD[512] | bcntS[512] | curDg[512] | curSg[512] |
    // baseD[512] | baseS[512] | row_ptr[NN+1] | dstn[NN] | esrc[NE] | pad |
    // aggb[NN*64] | xh[NN*64] | w1t[8192] | w2t[3072] | hwb[NN*20]
    float* srcn = (float*)d_ws;
    unsigned int* bcntD = (unsigned int*)(srcn + NN);
    unsigned int* bcntS = bcntD + 512;
    int* curDg = (int*)(bcntS + 512);
    int* curSg = curDg + 512;
    int* baseD = curSg + 512;
    int* baseS = baseD + 512;
    int* row_ptr = baseS + 512;
    float* dstn  = (float*)(row_ptr + NN + 1);
    int* esrc    = (int*)(dstn + NN);
    size_t ofs = (size_t)NN + 3072 + (NN + 1) + NN + NE;
    ofs = (ofs + 3) & ~(size_t)3;                 // 16B align
    unsigned short* aggb = (unsigned short*)((float*)d_ws + ofs);
    unsigned short* xh   = aggb + (size_t)NN * INF;
    unsigned short* w1t  = xh + (size_t)NN * INF;
    unsigned short* w2t  = w1t + 128 * 128;
    unsigned short* hwb  = w2t + 48 * 128;

    // edge-record scratch lives in d_out (9.6 MB of 16 MB) — dead before gather2 writes
    int* epartsD = (int*)d_out;                            // 6.4 MB
    unsigned short* epartsS = (unsigned short*)(epartsD + NE);  // 3.2 MB

    hipMemsetAsync(bcntD, 0, 2048 * sizeof(int), stream);  // bcntD|bcntS|curDg|curSg

    histconv_kernel<<<HB + 6252, 256, 0, stream>>>(src, dst, bcntD, bcntS,
                                                   x, W1, W2, xh, w1t, w2t);
    basescan_kernel<<<1, 512, 0, stream>>>(bcntD, bcntS, baseD, baseS);
    partition_kernel<<<PBLK, 512, 0, stream>>>(src, dst, baseD, baseS, curDg, curSg,
                                               epartsD, epartsS);
    pass2_kernel<<<NBK, 256, 0, stream>>>(epartsD, epartsS, baseD, baseS,
                                          bcntD, bcntS, row_ptr, esrc, srcn, dstn);
    gather1_kernel<<<(NN * 64 + 255) / 256, 256, 0, stream>>>(row_ptr, esrc, xh,
                                                              srcn, aggb);
    gemm12_kernel<<<(NN + 31) / 32, 256, 0, stream>>>(aggb, w1t, w2t, b1, dstn,
                                                      srcn, hwb);
    gather2_kernel<<<(NN * 64 + 255) / 256, 256, 0, stream>>>(row_ptr, esrc, hwb,
                                                              dstn, b2, out);
}

// Round 10
// 305.317 us; speedup vs baseline: 1.0565x; 1.0565x over previous
//
#include <hip/hip_runtime.h>

// GCN: 2-layer GraphConv, N=100000, E=1600000, 128 -> 128 -> 40 (fp32).
// Round 19: fused at full occupancy cap.
//   fused: 32 nodes/block, 4 waves x 8 nodes SERIAL single-stream gather
//          (R1 body, 28 VGPR proven) -> fits (256,8) 64-VGPR budget without
//          spill -> occupancy cap 100% (was 50% at (256,4), meas ~0.7xcap).
//          GEMM1 split (row-tile, nt-half) + GEMM2 waves 0/2, race-safe
//          barriers (R8-proven).
//   build: R5 BKSH=9 form; x->xh convert blocks merged into partition launch
//          (partition's 391 fat blocks underfill the GPU; convert streams on
//          idle CUs for free).
//   gather2: unchanged.
constexpr int NN   = 100000;
constexpr int NE   = 1600000;
constexpr int INF  = 128;
constexpr int NC   = 40;

constexpr int BKSH = 9;                        // 512 nodes per coarse bucket
constexpr int NBK  = (NN + 511) / 512;         // 196 buckets
constexpr int EPB  = 4096;                     // edges per partition block
constexpr int PBLK = (NE + EPB - 1) / EPB;     // 391
constexpr int CAP  = 14336;                    // pass2 LDS esrc capacity (56 KB)
constexpr int HB   = 391;                      // hist blocks
constexpr int CVB  = 6250;                     // convert blocks (NN*128/8 uint4 / 256)

typedef __attribute__((ext_vector_type(8))) short short8;
typedef __attribute__((ext_vector_type(4))) float f32x4;

__device__ __forceinline__ float bflo(unsigned int u) { return __uint_as_float(u << 16); }
__device__ __forceinline__ float bfhi(unsigned int u) { return __uint_as_float(u & 0xffff0000u); }
__device__ __forceinline__ unsigned short f2bf(float f) {          // RNE
    unsigned int u = __float_as_uint(f);
    return (unsigned short)((u + 0x7fffu + ((u >> 16) & 1u)) >> 16);
}
__device__ __forceinline__ unsigned int pack2(float a, float b) {
    return (unsigned int)f2bf(a) | ((unsigned int)f2bf(b) << 16);
}

// blocks 0..HB-1: coarse dst+src bucket histograms (LDS aggregated).
// block HB: W1 transpose->bf16. block HB+1: W2 transpose->bf16.
__global__ __launch_bounds__(256) void hist_kernel(const int* __restrict__ src,
                                                   const int* __restrict__ dst,
                                                   unsigned int* __restrict__ bcntD,
                                                   unsigned int* __restrict__ bcntS,
                                                   const float* __restrict__ W1,
                                                   const float* __restrict__ W2,
                                                   unsigned short* __restrict__ w1t,
                                                   unsigned short* __restrict__ w2t) {
    const int b = blockIdx.x;
    const int tid = threadIdx.x;
    if (b < HB) {
        __shared__ unsigned int hcD[NBK];
        __shared__ unsigned int hcS[NBK];
        for (int i = tid; i < NBK; i += 256) { hcD[i] = 0u; hcS[i] = 0u; }
        __syncthreads();
        int gid = b * 256 + tid;
        int stride = HB * 256;
        for (int e = gid; e < NE; e += stride) {
            atomicAdd(&hcD[dst[e] >> BKSH], 1u);
            atomicAdd(&hcS[src[e] >> BKSH], 1u);
        }
        __syncthreads();
        for (int i = tid; i < NBK; i += 256) {
            if (hcD[i]) atomicAdd(&bcntD[i], hcD[i]);
            if (hcS[i]) atomicAdd(&bcntS[i], hcS[i]);
        }
    } else if (b == HB) {
        for (int i = tid; i < 128 * 128; i += 256) {
            int k = i >> 7, n = i & 127;
            w1t[n * 128 + k] = f2bf(W1[i]);
        }
    } else {
        for (int i = tid; i < 48 * 128; i += 256) {
            int n = i >> 7, k = i & 127;
            w2t[i] = f2bf((n < NC) ? W2[k * NC + n] : 0.f);
        }
    }
}

// 1 block: exclusive scans of the 196 bucket counts (dst and src sides).
__global__ __launch_bounds__(256) void basescan_kernel(const unsigned int* __restrict__ bcntD,
                                                       const unsigned int* __restrict__ bcntS,
                                                       int* __restrict__ baseD,
                                                       int* __restrict__ baseS) {
    __shared__ int sc[256];
    const int tid = threadIdx.x;
    int v = (tid < NBK) ? (int)bcntD[tid] : 0;
    sc[tid] = v;
    __syncthreads();
    for (int off = 1; off < 256; off <<= 1) {
        int t = (tid >= off) ? sc[tid - off] : 0;
        __syncthreads();
        sc[tid] += t;
        __syncthreads();
    }
    if (tid < NBK) baseD[tid] = sc[tid] - v;
    __syncthreads();
    v = (tid < NBK) ? (int)bcntS[tid] : 0;
    sc[tid] = v;
    __syncthreads();
    for (int off = 1; off < 256; off <<= 1) {
        int t = (tid >= off) ? sc[tid - off] : 0;
        __syncthreads();
        sc[tid] += t;
        __syncthreads();
    }
    if (tid < NBK) baseS[tid] = sc[tid] - v;
}

// blocks 0..PBLK-1: dual partition (R5 form, bases precomputed).
// blocks PBLK..PBLK+CVB-1: x (fp32) -> xh (bf16), independent streaming.
__global__ __launch_bounds__(256) void partconv_kernel(const int* __restrict__ src,
                                                       const int* __restrict__ dst,
                                                       const int* __restrict__ baseD,
                                                       const int* __restrict__ baseS,
                                                       int* __restrict__ curD_g,
                                                       int* __restrict__ curS_g,
                                                       int* __restrict__ epartsD,
                                                       unsigned short* __restrict__ epartsS,
                                                       const float* __restrict__ x,
                                                       unsigned short* __restrict__ xh) {
    const int tid = threadIdx.x;
    if (blockIdx.x >= PBLK) {                    // ---- convert part ----
        int j = (blockIdx.x - PBLK) * 256 + tid; // uint4 index, N*128/8 = 1.6M
        float4 v0 = ((const float4*)x)[2 * j];
        float4 v1 = ((const float4*)x)[2 * j + 1];
        uint4 o;
        o.x = pack2(v0.x, v0.y);
        o.y = pack2(v0.z, v0.w);
        o.z = pack2(v1.x, v1.y);
        o.w = pack2(v1.z, v1.w);
        ((uint4*)xh)[j] = o;
        return;
    }
    __shared__ int sc[256];
    __shared__ int cntD[NBK], gadjD[NBK], curD[NBK];
    __shared__ int cntS[NBK], gadjS[NBK], curS[NBK];
    __shared__ int stageD[EPB];
    __shared__ unsigned short stageS[EPB];
    __shared__ unsigned char bidD[EPB];
    __shared__ unsigned char bidS[EPB];
    const int e0 = blockIdx.x * EPB;
    const int total = min(EPB, NE - e0);

    for (int i = tid; i < NBK; i += 256) { cntD[i] = 0; cntS[i] = 0; }
    __syncthreads();
    // phase A: count per bucket (both keys)
    for (int i = tid; i < total; i += 256) {
        atomicAdd(&cntD[dst[e0 + i] >> BKSH], 1);
        atomicAdd(&cntS[src[e0 + i] >> BKSH], 1);
    }
    __syncthreads();
    // exclusive scans of cntD, cntS; reserve global ranges
    {
        int v = (tid < NBK) ? cntD[tid] : 0;
        sc[tid] = v;
        __syncthreads();
        for (int off = 1; off < 256; off <<= 1) {
            int t = (tid >= off) ? sc[tid - off] : 0;
            __syncthreads();
            sc[tid] += t;
            __syncthreads();
        }
        if (tid < NBK) {
            int excl = sc[tid] - v;
            curD[tid] = excl;
            int g = (v > 0) ? atomicAdd(&curD_g[tid], v) : 0;   // zero-based
            gadjD[tid] = baseD[tid] + g - excl;
        }
        __syncthreads();
        v = (tid < NBK) ? cntS[tid] : 0;
        sc[tid] = v;
        __syncthreads();
        for (int off = 1; off < 256; off <<= 1) {
            int t = (tid >= off) ? sc[tid - off] : 0;
            __syncthreads();
            sc[tid] += t;
            __syncthreads();
        }
        if (tid < NBK) {
            int excl = sc[tid] - v;
            curS[tid] = excl;
            int g = (v > 0) ? atomicAdd(&curS_g[tid], v) : 0;
            gadjS[tid] = baseS[tid] + g - excl;
        }
    }
    __syncthreads();
    // phase B: re-read edges, stage grouped by bucket (both keys)
    for (int i = tid; i < total; i += 256) {
        int s = src[e0 + i];
        int d = dst[e0 + i];
        int bD = d >> BKSH;
        int offD = atomicAdd(&curD[bD], 1);
        stageD[offD] = s | ((d - (bD << BKSH)) << 17);
        bidD[offD] = (unsigned char)bD;
        int bS = s >> BKSH;
        int offS = atomicAdd(&curS[bS], 1);
        stageS[offS] = (unsigned short)(s - (bS << BKSH));
        bidS[offS] = (unsigned char)bS;
    }
    __syncthreads();
    // dumps: consecutive j within a bucket-run -> consecutive global addresses
    for (int j = tid; j < total; j += 256) {
        int b = bidD[j];
        epartsD[gadjD[b] + j] = stageD[j];
    }
    for (int j = tid; j < total; j += 256) {
        int b = bidS[j];
        epartsS[gadjS[b] + j] = stageS[j];
    }
}

// per-bucket: dst CSR (hist+scan+LDS scatter -> row_ptr, dstn, esrc) AND
// src out-degree hist -> srcn. Bases read from basescan output.
__global__ __launch_bounds__(512) void pass2_kernel(const int* __restrict__ epartsD,
                                                    const unsigned short* __restrict__ epartsS,
                                                    const int* __restrict__ baseD,
                                                    const int* __restrict__ baseS_g,
                                                    const unsigned int* __restrict__ bcntD,
                                                    const unsigned int* __restrict__ bcntS,
                                                    int* __restrict__ row_ptr,
                                                    int* __restrict__ esrc,
                                                    float* __restrict__ srcn,
                                                    float* __restrict__ dstn) {
    __shared__ int hist[512];
    __shared__ int cur[512];
    __shared__ int histS[512];
    __shared__ int lesrc[CAP];
    const int tid = threadIdx.x;
    const int b = blockIdx.x;

    const int base  = baseD[b];
    const int cnt   = (int)bcntD[b];
    const int baseS = baseS_g[b];
    const int cntS  = (int)bcntS[b];
    const int n0 = b << BKSH;
    const int nloc = min(512, NN - n0);

    hist[tid] = 0;
    histS[tid] = 0;
    __syncthreads();
    for (int j = tid; j < cnt; j += 512)
        atomicAdd(&hist[epartsD[base + j] >> 17], 1);
    for (int j = tid; j < cntS; j += 512)
        atomicAdd(&histS[(int)epartsS[baseS + j]], 1);
    __syncthreads();
    int myc = hist[tid];
    int mycS = histS[tid];
    for (int off = 1; off < 512; off <<= 1) {
        int t = (tid >= off) ? hist[tid - off] : 0;
        __syncthreads();
        hist[tid] += t;
        __syncthreads();
    }
    int excl = hist[tid] - myc;
    cur[tid] = excl;
    if (tid < nloc) {
        int g = n0 + tid;
        row_ptr[g] = base + excl;
        dstn[g] = rsqrtf(fmaxf((float)myc, 1.0f));    // dst_norm (in-degree)
        srcn[g] = rsqrtf(fmaxf((float)mycS, 1.0f));   // src_norm (out-degree)
    }
    if (b == NBK - 1 && tid == 0) row_ptr[NN] = NE;
    __syncthreads();
    if (cnt <= CAP) {
        for (int j = tid; j < cnt; j += 512) {
            int rec = epartsD[base + j];
            int pos = atomicAdd(&cur[rec >> 17], 1);
            lesrc[pos] = rec & 0x1FFFF;
        }
        __syncthreads();
        for (int j = tid; j < cnt; j += 512) esrc[base + j] = lesrc[j];
    } else {
        for (int j = tid; j < cnt; j += 512) {
            int rec = epartsD[base + j];
            int pos = atomicAdd(&cur[rec >> 17], 1);
            esrc[base + pos] = rec & 0x1FFFF;
        }
    }
}

// Fused gather1 + GEMM1 + GEMM2. 32 nodes/block, 4 waves x 8 nodes SERIAL
// (single-stream R1 gather body, 28 VGPR proven -> fits (256,8) 64-VGPR
// budget). 3125 blocks. GEMM1 split (row-tile, nt-half) = (wv>>1, wv&1);
// race-safe: gather -> barrier -> all waves snapshot A-frags -> barrier ->
// MFMA + h into At -> barrier -> GEMM2 (waves 0/2).
__global__ __launch_bounds__(256, 8) void fused_kernel(const int* __restrict__ row_ptr,
                                                       const int* __restrict__ esrc,
                                                       const unsigned short* __restrict__ xh,
                                                       const float* __restrict__ srcn,
                                                       const unsigned short* __restrict__ w1t,
                                                       const unsigned short* __restrict__ w2t,
                                                       const float* __restrict__ b1,
                                                       const float* __restrict__ dstn,
                                                       unsigned short* __restrict__ hwb) {
    __shared__ unsigned short At[32 * 128];    // 8 KB: agg tile, then h tile
    __shared__ float dn[32], sn[32], b1l[128];
    const int tid  = threadIdx.x;
    const int r0   = blockIdx.x * 32;
    const int wv   = tid >> 6;
    const int lane = tid & 63;

    if (tid < 32) {
        int r = r0 + tid;
        dn[tid] = (r < NN) ? dstn[r] : 0.f;
        sn[tid] = (r < NN) ? srcn[r] : 0.f;
    }
    if (tid >= 64 && tid < 192) b1l[tid - 64] = b1[tid - 64];
    __syncthreads();

    // ---- phase 1: gather 8 nodes serially (R1 single-stream body) ----
    const int quad = lane >> 4;       // edge-slot group 0..3
    const int l16  = lane & 15;       // uint4 index within 256 B row
    for (int i = 0; i < 8; ++i) {
        const int node = r0 + wv * 8 + i;
        float a0 = 0.f, a1 = 0.f, a2 = 0.f, a3 = 0.f;
        float a4 = 0.f, a5 = 0.f, a6 = 0.f, a7 = 0.f;
        if (node < NN) {
            int beg = __builtin_amdgcn_readfirstlane(row_ptr[node]);
            int end = __builtin_amdgcn_readfirstlane(row_ptr[node + 1]);
            for (int e = beg; e < end; e += 16) {
                const int rem = end - e;
                int s[4];
#pragma unroll
                for (int t = 0; t < 4; ++t) {
                    int slot = t * 4 + quad;
                    s[t] = esrc[(slot < rem) ? (e + slot) : beg];
                }
                float n[4];
                uint4 u[4];
#pragma unroll
                for (int t = 0; t < 4; ++t) {
                    int slot = t * 4 + quad;
                    n[t] = (slot < rem) ? srcn[s[t]] : 0.f;
                    u[t] = ((const uint4*)(xh + (size_t)s[t] * INF))[l16];
                }
#pragma unroll
                for (int t = 0; t < 4; ++t) {
                    a0 += bflo(u[t].x) * n[t]; a1 += bfhi(u[t].x) * n[t];
                    a2 += bflo(u[t].y) * n[t]; a3 += bfhi(u[t].y) * n[t];
                    a4 += bflo(u[t].z) * n[t]; a5 += bfhi(u[t].z) * n[t];
                    a6 += bflo(u[t].w) * n[t]; a7 += bfhi(u[t].w) * n[t];
                }
            }
        }
        a0 += __shfl_down(a0, 32); a1 += __shfl_down(a1, 32);
        a2 += __shfl_down(a2, 32); a3 += __shfl_down(a3, 32);
        a4 += __shfl_down(a4, 32); a5 += __shfl_down(a5, 32);
        a6 += __shfl_down(a6, 32); a7 += __shfl_down(a7, 32);
        a0 += __shfl_down(a0, 16); a1 += __shfl_down(a1, 16);
        a2 += __shfl_down(a2, 16); a3 += __shfl_down(a3, 16);
        a4 += __shfl_down(a4, 16); a5 += __shfl_down(a5, 16);
        a6 += __shfl_down(a6, 16); a7 += __shfl_down(a7, 16);
        if (lane < 16) {
            uint4 o;
            o.x = pack2(a0, a1);
            o.y = pack2(a2, a3);
            o.z = pack2(a4, a5);
            o.w = pack2(a6, a7);
            *(uint4*)&At[(wv * 8 + i) * 128 + l16 * 8] = o;
        }
    }
    __syncthreads();   // cross-wave: GEMM reads rows gathered by other waves

    // ---- phase 2: MFMA GEMM1 (+relu), split (row-tile, nt-half) ----
    const int lrow  = lane & 15;
    const int lquad = lane >> 4;
    const int rt    = wv >> 1;            // row-tile 0 (rows 0-15) / 1 (16-31)
    const int ntB   = (wv & 1) * 4;       // nt-half 0-3 / 4-7

    // ALL waves snapshot their A-frags to registers before ANY h write.
    short8 afrag[4];
#pragma unroll
    for (int ks = 0; ks < 4; ++ks)
        afrag[ks] = *(const short8*)&At[(rt * 16 + lrow) * 128 + ks * 32 + lquad * 8];
    __syncthreads();   // agg reads complete before h overwrites At

    float hreg[4][4];
#pragma unroll
    for (int nt2 = 0; nt2 < 4; ++nt2) {
        f32x4 acc = {0.f, 0.f, 0.f, 0.f};
#pragma unroll
        for (int ks = 0; ks < 4; ++ks) {
            short8 bfr = *(const short8*)&w1t[((ntB + nt2) * 16 + lrow) * 128 + ks * 32 + lquad * 8];
            acc = __builtin_amdgcn_mfma_f32_16x16x32_bf16(afrag[ks], bfr, acc, 0, 0, 0);
        }
#pragma unroll
        for (int i = 0; i < 4; ++i) hreg[nt2][i] = acc[i];
    }
#pragma unroll
    for (int nt2 = 0; nt2 < 4; ++nt2) {
        int col = (ntB + nt2) * 16 + lrow;
        float bb = b1l[col];
#pragma unroll
        for (int i = 0; i < 4; ++i) {
            int row = rt * 16 + lquad * 4 + i;
            At[row * 128 + col] = f2bf(fmaxf(hreg[nt2][i] * dn[row] + bb, 0.f));
        }
    }
    __syncthreads();   // cross-wave: GEMM2 reads h cols written by nt-half peer

    // ---- GEMM2 on waves 0/2 (row-tile wv>>1) ----
    if ((wv & 1) == 0) {
        short8 hf[4];
#pragma unroll
        for (int ks = 0; ks < 4; ++ks)
            hf[ks] = *(const short8*)&At[(rt * 16 + lrow) * 128 + ks * 32 + lquad * 8];
#pragma unroll
        for (int nt = 0; nt < 3; ++nt) {
            f32x4 acc = {0.f, 0.f, 0.f, 0.f};
#pragma unroll
            for (int ks = 0; ks < 4; ++ks) {
                short8 bfr = *(const short8*)&w2t[(nt * 16 + lrow) * 128 + ks * 32 + lquad * 8];
                acc = __builtin_amdgcn_mfma_f32_16x16x32_bf16(hf[ks], bfr, acc, 0, 0, 0);
            }
            int col = nt * 16 + lrow;
            if (col < NC) {
#pragma unroll
                for (int i = 0; i < 4; ++i) {
                    int row = rt * 16 + lquad * 4 + i;
                    int grow = r0 + row;
                    if (grow < NN)
                        hwb[(size_t)grow * NC + col] = f2bf(acc[i] * sn[row]);
                }
            }
        }
    }
}

// one wave per node. lane = g*10+j (g<6, j<10): 6 edge slots, each edge's
// 80 B row read by 10 lanes as uint2 (4 bf16). Predicated 18-edge batches
// (3 independent loads per lane in flight); invalid slots clamp to edge `beg`
// with multiplicative zero mask. fp32 acc; shfl reduce into lanes 0..9,
// which store float4 with fused *dstn + b2.
__global__ __launch_bounds__(256) void gather2_kernel(const int* __restrict__ row_ptr,
                                                      const int* __restrict__ esrc,
                                                      const unsigned short* __restrict__ hwb,
                                                      const float* __restrict__ dst_norm,
                                                      const float* __restrict__ b2,
                                                      float* __restrict__ out) {
    int node = (blockIdx.x * blockDim.x + threadIdx.x) >> 6;
    int lane = threadIdx.x & 63;
    if (node >= NN) return;
    int beg = __builtin_amdgcn_readfirstlane(row_ptr[node]);
    int end = __builtin_amdgcn_readfirstlane(row_ptr[node + 1]);
    const int g = lane / 10;          // edge slot 0..5 (g==6: lanes 60-63 masked)
    const int j = lane - g * 10;      // uint2 index within 80 B row
    const bool active = (g < 6);
    float4 acc = make_float4(0.f, 0.f, 0.f, 0.f);
    for (int e = beg; e < end; e += 18) {
        const int rem = end - e;
        int s[3];
        float m[3];
#pragma unroll
        for (int q = 0; q < 3; ++q) {
            int slot = q * 6 + g;
            bool v = active && (slot < rem);
            int idx = v ? (e + slot) : beg;
            s[q] = esrc[idx];
            m[q] = v ? 1.f : 0.f;
        }
        uint2 u[3];
#pragma unroll
        for (int q = 0; q < 3; ++q)
            u[q] = ((const uint2*)(hwb + (size_t)s[q] * NC))[j];
#pragma unroll
        for (int q = 0; q < 3; ++q) {
            acc.x += bflo(u[q].x) * m[q];
            acc.y += bfhi(u[q].x) * m[q];
            acc.z += bflo(u[q].y) * m[q];
            acc.w += bfhi(u[q].y) * m[q];
        }
    }
    float4 tot = acc;
#pragma unroll
    for (int k = 1; k < 6; ++k) {
        tot.x += __shfl(acc.x, j + 10 * k);
        tot.y += __shfl(acc.y, j + 10 * k);
        tot.z += __shfl(acc.z, j + 10 * k);
        tot.w += __shfl(acc.w, j + 10 * k);
    }
    if (lane < 10) {
        float dnv = dst_norm[node];
        float4 bb = ((const float4*)b2)[j];
        float4 o;
        o.x = tot.x * dnv + bb.x;
        o.y = tot.y * dnv + bb.y;
        o.z = tot.z * dnv + bb.z;
        o.w = tot.w * dnv + bb.w;
        ((float4*)(out + (size_t)node * NC))[j] = o;
    }
}

extern "C" void kernel_launch(void* const* d_in, const int* in_sizes, int n_in,
                              void* d_out, int out_size, void* d_ws, size_t ws_size,
                              hipStream_t stream) {
    const float* x   = (const float*)d_in[0];
    const float* W1  = (const float*)d_in[1];
    const float* b1  = (const float*)d_in[2];
    const float* W2  = (const float*)d_in[3];
    const float* b2  = (const float*)d_in[4];
    const int*   src = (const int*)d_in[5];
    const int*   dst = (const int*)d_in[6];
    float* out = (float*)d_out;

    // workspace (4B units):
    // srcn[NN] | bcntD[256] | bcntS[256] | curD[256] | curS[256] |
    // baseD[256] | baseS[256] | row_ptr[NN+1] | dstn[NN] | esrc[NE] | pad |
    // xh[NN*64] | w1t[8192] | w2t[3072] | hwb[NN*20]
    float* srcn = (float*)d_ws;
    unsigned int* bcntD = (unsigned int*)(srcn + NN);
    unsigned int* bcntS = bcntD + 256;
    int* curD  = (int*)(bcntS + 256);
    int* curS  = curD + 256;
    int* baseD = curS + 256;
    int* baseS = baseD + 256;
    int* row_ptr = baseS + 256;
    float* dstn  = (float*)(row_ptr + NN + 1);
    int* esrc    = (int*)(dstn + NN);
    size_t ofs = (size_t)NN + 1536 + (NN + 1) + NN + NE;
    ofs = (ofs + 3) & ~(size_t)3;                 // 16B align
    unsigned short* xh   = (unsigned short*)((float*)d_ws + ofs);
    unsigned short* w1t  = xh + (size_t)NN * INF;
    unsigned short* w2t  = w1t + 128 * 128;
    unsigned short* hwb  = w2t + 48 * 128;

    // edge-record scratch lives in d_out (9.6 MB of 16 MB) — dead before gather2 writes
    int* epartsD = (int*)d_out;                            // 6.4 MB
    unsigned short* epartsS = (unsigned short*)(epartsD + NE);  // 3.2 MB

    hipMemsetAsync(bcntD, 0, 1024 * sizeof(int), stream);  // bcntD|bcntS|curD|curS

    hist_kernel<<<HB + 2, 256, 0, stream>>>(src, dst, bcntD, bcntS,
                                            W1, W2, w1t, w2t);
    basescan_kernel<<<1, 256, 0, stream>>>(bcntD, bcntS, baseD, baseS);
    partconv_kernel<<<PBLK + CVB, 256, 0, stream>>>(src, dst, baseD, baseS,
                                                    curD, curS, epartsD, epartsS,
                                                    x, xh);
    pass2_kernel<<<NBK, 512, 0, stream>>>(epartsD, epartsS, baseD, baseS,
                                          bcntD, bcntS, row_ptr, esrc, srcn, dstn);
    fused_kernel<<<(NN + 31) / 32, 256, 0, stream>>>(row_ptr, esrc, xh, srcn,
                                                     w1t, w2t, b1, dstn, hwb);
    gather2_kernel<<<(NN * 64 + 255) / 256, 256, 0, stream>>>(row_ptr, esrc, hwb,
                                                              dstn, b2, out);
}

// Round 11
// 278.327 us; speedup vs baseline: 1.1590x; 1.0970x over previous
//
#include <hip/hip_runtime.h>

// GCN: 2-layer GraphConv, N=100000, E=1600000, 128 -> 128 -> 40 (fp32).
// Round 20: fixed-capacity buckets — hist + basescan deleted.
//   Buckets of 512 dst (and src) nodes get fixed capacity CAPB=10240 records
//   (mean 8192, sigma~90 -> 22-sigma margin; input graph deterministic).
//   Bases are constants b*CAPB; partition reserves ranges with the same
//   global cursors it always used; pass2 reads final counts from cursors.
//   esrc is gapped -> explicit row_beg/row_end arrays (same 2 scalar loads).
//   partconv also carries x->xh convert + W1/W2 transpose blocks.
//   fused (R19 form, 108us @ 69% occ) and gather2 unchanged in structure.
constexpr int NN   = 100000;
constexpr int NE   = 1600000;
constexpr int INF  = 128;
constexpr int NC   = 40;

constexpr int BKSH = 9;                        // 512 nodes per coarse bucket
constexpr int NBK  = (NN + 511) / 512;         // 196 buckets
constexpr int CAPB = 10240;                    // fixed records per bucket
constexpr int EPB  = 4096;                     // edges per partition block
constexpr int PBLK = (NE + EPB - 1) / EPB;     // 391
constexpr int CVB  = 6250;                     // convert blocks (NN*128/8 / 256)

typedef __attribute__((ext_vector_type(8))) short short8;
typedef __attribute__((ext_vector_type(4))) float f32x4;

__device__ __forceinline__ float bflo(unsigned int u) { return __uint_as_float(u << 16); }
__device__ __forceinline__ float bfhi(unsigned int u) { return __uint_as_float(u & 0xffff0000u); }
__device__ __forceinline__ unsigned short f2bf(float f) {          // RNE
    unsigned int u = __float_as_uint(f);
    return (unsigned short)((u + 0x7fffu + ((u >> 16) & 1u)) >> 16);
}
__device__ __forceinline__ unsigned int pack2(float a, float b) {
    return (unsigned int)f2bf(a) | ((unsigned int)f2bf(b) << 16);
}

// blocks 0..PBLK-1: dual partition into fixed-capacity buckets.
// blocks PBLK..PBLK+CVB-1: x (fp32) -> xh (bf16).
// last two blocks: W1 / W2 transpose -> bf16.
__global__ __launch_bounds__(256) void partconv_kernel(const int* __restrict__ src,
                                                       const int* __restrict__ dst,
                                                       int* __restrict__ curD_g,
                                                       int* __restrict__ curS_g,
                                                       int* __restrict__ epartsD,
                                                       unsigned short* __restrict__ epartsS,
                                                       const float* __restrict__ x,
                                                       unsigned short* __restrict__ xh,
                                                       const float* __restrict__ W1,
                                                       const float* __restrict__ W2,
                                                       unsigned short* __restrict__ w1t,
                                                       unsigned short* __restrict__ w2t) {
    const int tid = threadIdx.x;
    if (blockIdx.x >= PBLK) {
        int cb = blockIdx.x - PBLK;
        if (cb < CVB) {                          // ---- x convert ----
            int j = cb * 256 + tid;              // uint4 index, N*128/8 = 1.6M
            float4 v0 = ((const float4*)x)[2 * j];
            float4 v1 = ((const float4*)x)[2 * j + 1];
            uint4 o;
            o.x = pack2(v0.x, v0.y);
            o.y = pack2(v0.z, v0.w);
            o.z = pack2(v1.x, v1.y);
            o.w = pack2(v1.z, v1.w);
            ((uint4*)xh)[j] = o;
        } else if (cb == CVB) {                  // ---- W1 transpose ----
            for (int i = tid; i < 128 * 128; i += 256) {
                int k = i >> 7, n = i & 127;
                w1t[n * 128 + k] = f2bf(W1[i]);
            }
        } else {                                 // ---- W2 transpose ----
            for (int i = tid; i < 48 * 128; i += 256) {
                int n = i >> 7, k = i & 127;
                w2t[i] = f2bf((n < NC) ? W2[k * NC + n] : 0.f);
            }
        }
        return;
    }
    // ---- partition part ----
    __shared__ int sc[256];
    __shared__ int cntD[NBK], gadjD[NBK], curD[NBK];
    __shared__ int cntS[NBK], gadjS[NBK], curS[NBK];
    __shared__ int stageD[EPB];
    __shared__ unsigned short stageS[EPB];
    __shared__ unsigned char bidD[EPB];
    __shared__ unsigned char bidS[EPB];
    const int e0 = blockIdx.x * EPB;
    const int total = min(EPB, NE - e0);

    for (int i = tid; i < NBK; i += 256) { cntD[i] = 0; cntS[i] = 0; }
    __syncthreads();
    // phase A: count per bucket (both keys)
    for (int i = tid; i < total; i += 256) {
        atomicAdd(&cntD[dst[e0 + i] >> BKSH], 1);
        atomicAdd(&cntS[src[e0 + i] >> BKSH], 1);
    }
    __syncthreads();
    // exclusive scans of cntD, cntS; reserve global ranges (base = b*CAPB)
    {
        int v = (tid < NBK) ? cntD[tid] : 0;
        sc[tid] = v;
        __syncthreads();
        for (int off = 1; off < 256; off <<= 1) {
            int t = (tid >= off) ? sc[tid - off] : 0;
            __syncthreads();
            sc[tid] += t;
            __syncthreads();
        }
        if (tid < NBK) {
            int excl = sc[tid] - v;
            curD[tid] = excl;
            int g = (v > 0) ? atomicAdd(&curD_g[tid], v) : 0;
            gadjD[tid] = tid * CAPB + g - excl;
        }
        __syncthreads();
        v = (tid < NBK) ? cntS[tid] : 0;
        sc[tid] = v;
        __syncthreads();
        for (int off = 1; off < 256; off <<= 1) {
            int t = (tid >= off) ? sc[tid - off] : 0;
            __syncthreads();
            sc[tid] += t;
            __syncthreads();
        }
        if (tid < NBK) {
            int excl = sc[tid] - v;
            curS[tid] = excl;
            int g = (v > 0) ? atomicAdd(&curS_g[tid], v) : 0;
            gadjS[tid] = tid * CAPB + g - excl;
        }
    }
    __syncthreads();
    // phase B: re-read edges, stage grouped by bucket (both keys)
    for (int i = tid; i < total; i += 256) {
        int s = src[e0 + i];
        int d = dst[e0 + i];
        int bD = d >> BKSH;
        int offD = atomicAdd(&curD[bD], 1);
        stageD[offD] = s | ((d - (bD << BKSH)) << 17);
        bidD[offD] = (unsigned char)bD;
        int bS = s >> BKSH;
        int offS = atomicAdd(&curS[bS], 1);
        stageS[offS] = (unsigned short)(s - (bS << BKSH));
        bidS[offS] = (unsigned char)bS;
    }
    __syncthreads();
    // dumps: consecutive j within a bucket-run -> consecutive global addresses
    for (int j = tid; j < total; j += 256) {
        int b = bidD[j];
        epartsD[gadjD[b] + j] = stageD[j];
    }
    for (int j = tid; j < total; j += 256) {
        int b = bidS[j];
        epartsS[gadjS[b] + j] = stageS[j];
    }
}

// per-bucket: dst CSR (hist+scan+LDS scatter -> row_beg/row_end, dstn, esrc)
// AND src out-degree hist -> srcn. Bases are b*CAPB; counts from cursors.
__global__ __launch_bounds__(512) void pass2_kernel(const int* __restrict__ epartsD,
                                                    const unsigned short* __restrict__ epartsS,
                                                    const int* __restrict__ curD_g,
                                                    const int* __restrict__ curS_g,
                                                    int* __restrict__ row_beg,
                                                    int* __restrict__ row_end,
                                                    int* __restrict__ esrc,
                                                    float* __restrict__ srcn,
                                                    float* __restrict__ dstn) {
    __shared__ int hist[512];
    __shared__ int cur[512];
    __shared__ int histS[512];
    __shared__ int lesrc[CAPB];
    const int tid = threadIdx.x;
    const int b = blockIdx.x;

    const int base  = b * CAPB;
    const int cnt   = curD_g[b];
    const int cntS  = curS_g[b];
    const int n0 = b << BKSH;
    const int nloc = min(512, NN - n0);

    hist[tid] = 0;
    histS[tid] = 0;
    __syncthreads();
    for (int j = tid; j < cnt; j += 512)
        atomicAdd(&hist[epartsD[base + j] >> 17], 1);
    for (int j = tid; j < cntS; j += 512)
        atomicAdd(&histS[(int)epartsS[base + j]], 1);
    __syncthreads();
    int myc = hist[tid];
    int mycS = histS[tid];
    for (int off = 1; off < 512; off <<= 1) {
        int t = (tid >= off) ? hist[tid - off] : 0;
        __syncthreads();
        hist[tid] += t;
        __syncthreads();
    }
    int excl = hist[tid] - myc;
    cur[tid] = excl;
    if (tid < nloc) {
        int g = n0 + tid;
        row_beg[g] = base + excl;
        row_end[g] = base + excl + myc;
        dstn[g] = rsqrtf(fmaxf((float)myc, 1.0f));    // dst_norm (in-degree)
        srcn[g] = rsqrtf(fmaxf((float)mycS, 1.0f));   // src_norm (out-degree)
    }
    __syncthreads();
    for (int j = tid; j < cnt; j += 512) {
        int rec = epartsD[base + j];
        int pos = atomicAdd(&cur[rec >> 17], 1);
        lesrc[pos] = rec & 0x1FFFF;
    }
    __syncthreads();
    for (int j = tid; j < cnt; j += 512) esrc[base + j] = lesrc[j];
}

// Fused gather1 + GEMM1 + GEMM2. 32 nodes/block, 4 waves x 8 nodes serial
// (single-stream gather body, 28 VGPR), (256,8), 3125 blocks.
// GEMM1 split (row-tile, nt-half) = (wv>>1, wv&1); race-safe barriers.
__global__ __launch_bounds__(256, 8) void fused_kernel(const int* __restrict__ row_beg,
                                                       const int* __restrict__ row_end,
                                                       const int* __restrict__ esrc,
                                                       const unsigned short* __restrict__ xh,
                                                       const float* __restrict__ srcn,
                                                       const unsigned short* __restrict__ w1t,
                                                       const unsigned short* __restrict__ w2t,
                                                       const float* __restrict__ b1,
                                                       const float* __restrict__ dstn,
                                                       unsigned short* __restrict__ hwb) {
    __shared__ unsigned short At[32 * 128];    // 8 KB: agg tile, then h tile
    __shared__ float dn[32], sn[32], b1l[128];
    const int tid  = threadIdx.x;
    const int r0   = blockIdx.x * 32;
    const int wv   = tid >> 6;
    const int lane = tid & 63;

    if (tid < 32) {
        int r = r0 + tid;
        dn[tid] = (r < NN) ? dstn[r] : 0.f;
        sn[tid] = (r < NN) ? srcn[r] : 0.f;
    }
    if (tid >= 64 && tid < 192) b1l[tid - 64] = b1[tid - 64];
    __syncthreads();

    // ---- phase 1: gather 8 nodes serially (single-stream body) ----
    const int quad = lane >> 4;       // edge-slot group 0..3
    const int l16  = lane & 15;       // uint4 index within 256 B row
    for (int i = 0; i < 8; ++i) {
        const int node = r0 + wv * 8 + i;
        float a0 = 0.f, a1 = 0.f, a2 = 0.f, a3 = 0.f;
        float a4 = 0.f, a5 = 0.f, a6 = 0.f, a7 = 0.f;
        if (node < NN) {
            int beg = __builtin_amdgcn_readfirstlane(row_beg[node]);
            int end = __builtin_amdgcn_readfirstlane(row_end[node]);
            for (int e = beg; e < end; e += 16) {
                const int rem = end - e;
                int s[4];
#pragma unroll
                for (int t = 0; t < 4; ++t) {
                    int slot = t * 4 + quad;
                    s[t] = esrc[(slot < rem) ? (e + slot) : beg];
                }
                float n[4];
                uint4 u[4];
#pragma unroll
                for (int t = 0; t < 4; ++t) {
                    int slot = t * 4 + quad;
                    n[t] = (slot < rem) ? srcn[s[t]] : 0.f;
                    u[t] = ((const uint4*)(xh + (size_t)s[t] * INF))[l16];
                }
#pragma unroll
                for (int t = 0; t < 4; ++t) {
                    a0 += bflo(u[t].x) * n[t]; a1 += bfhi(u[t].x) * n[t];
                    a2 += bflo(u[t].y) * n[t]; a3 += bfhi(u[t].y) * n[t];
                    a4 += bflo(u[t].z) * n[t]; a5 += bfhi(u[t].z) * n[t];
                    a6 += bflo(u[t].w) * n[t]; a7 += bfhi(u[t].w) * n[t];
                }
            }
        }
        a0 += __shfl_down(a0, 32); a1 += __shfl_down(a1, 32);
        a2 += __shfl_down(a2, 32); a3 += __shfl_down(a3, 32);
        a4 += __shfl_down(a4, 32); a5 += __shfl_down(a5, 32);
        a6 += __shfl_down(a6, 32); a7 += __shfl_down(a7, 32);
        a0 += __shfl_down(a0, 16); a1 += __shfl_down(a1, 16);
        a2 += __shfl_down(a2, 16); a3 += __shfl_down(a3, 16);
        a4 += __shfl_down(a4, 16); a5 += __shfl_down(a5, 16);
        a6 += __shfl_down(a6, 16); a7 += __shfl_down(a7, 16);
        if (lane < 16) {
            uint4 o;
            o.x = pack2(a0, a1);
            o.y = pack2(a2, a3);
            o.z = pack2(a4, a5);
            o.w = pack2(a6, a7);
            *(uint4*)&At[(wv * 8 + i) * 128 + l16 * 8] = o;
        }
    }
    __syncthreads();   // cross-wave: GEMM reads rows gathered by other waves

    // ---- phase 2: MFMA GEMM1 (+relu), split (row-tile, nt-half) ----
    const int lrow  = lane & 15;
    const int lquad = lane >> 4;
    const int rt    = wv >> 1;            // row-tile 0 (rows 0-15) / 1 (16-31)
    const int ntB   = (wv & 1) * 4;       // nt-half 0-3 / 4-7

    // ALL waves snapshot their A-frags to registers before ANY h write.
    short8 afrag[4];
#pragma unroll
    for (int ks = 0; ks < 4; ++ks)
        afrag[ks] = *(const short8*)&At[(rt * 16 + lrow) * 128 + ks * 32 + lquad * 8];
    __syncthreads();   // agg reads complete before h overwrites At

    float hreg[4][4];
#pragma unroll
    for (int nt2 = 0; nt2 < 4; ++nt2) {
        f32x4 acc = {0.f, 0.f, 0.f, 0.f};
#pragma unroll
        for (int ks = 0; ks < 4; ++ks) {
            short8 bfr = *(const short8*)&w1t[((ntB + nt2) * 16 + lrow) * 128 + ks * 32 + lquad * 8];
            acc = __builtin_amdgcn_mfma_f32_16x16x32_bf16(afrag[ks], bfr, acc, 0, 0, 0);
        }
#pragma unroll
        for (int i = 0; i < 4; ++i) hreg[nt2][i] = acc[i];
    }
#pragma unroll
    for (int nt2 = 0; nt2 < 4; ++nt2) {
        int col = (ntB + nt2) * 16 + lrow;
        float bb = b1l[col];
#pragma unroll
        for (int i = 0; i < 4; ++i) {
            int row = rt * 16 + lquad * 4 + i;
            At[row * 128 + col] = f2bf(fmaxf(hreg[nt2][i] * dn[row] + bb, 0.f));
        }
    }
    __syncthreads();   // cross-wave: GEMM2 reads h cols written by nt-half peer

    // ---- GEMM2 on waves 0/2 (row-tile wv>>1) ----
    if ((wv & 1) == 0) {
        short8 hf[4];
#pragma unroll
        for (int ks = 0; ks < 4; ++ks)
            hf[ks] = *(const short8*)&At[(rt * 16 + lrow) * 128 + ks * 32 + lquad * 8];
#pragma unroll
        for (int nt = 0; nt < 3; ++nt) {
            f32x4 acc = {0.f, 0.f, 0.f, 0.f};
#pragma unroll
            for (int ks = 0; ks < 4; ++ks) {
                short8 bfr = *(const short8*)&w2t[(nt * 16 + lrow) * 128 + ks * 32 + lquad * 8];
                acc = __builtin_amdgcn_mfma_f32_16x16x32_bf16(hf[ks], bfr, acc, 0, 0, 0);
            }
            int col = nt * 16 + lrow;
            if (col < NC) {
#pragma unroll
                for (int i = 0; i < 4; ++i) {
                    int row = rt * 16 + lquad * 4 + i;
                    int grow = r0 + row;
                    if (grow < NN)
                        hwb[(size_t)grow * NC + col] = f2bf(acc[i] * sn[row]);
                }
            }
        }
    }
}

// one wave per node. lane = g*10+j (g<6, j<10): 6 edge slots, each edge's
// 80 B row read by 10 lanes as uint2 (4 bf16). Predicated 18-edge batches;
// invalid slots clamp to edge `beg` with multiplicative zero mask. fp32 acc;
// shfl reduce into lanes 0..9, which store float4 with fused *dstn + b2.
__global__ __launch_bounds__(256) void gather2_kernel(const int* __restrict__ row_beg,
                                                      const int* __restrict__ row_end,
                                                      const int* __restrict__ esrc,
                                                      const unsigned short* __restrict__ hwb,
                                                      const float* __restrict__ dst_norm,
                                                      const float* __restrict__ b2,
                                                      float* __restrict__ out) {
    int node = (blockIdx.x * blockDim.x + threadIdx.x) >> 6;
    int lane = threadIdx.x & 63;
    if (node >= NN) return;
    int beg = __builtin_amdgcn_readfirstlane(row_beg[node]);
    int end = __builtin_amdgcn_readfirstlane(row_end[node]);
    const int g = lane / 10;          // edge slot 0..5 (g==6: lanes 60-63 masked)
    const int j = lane - g * 10;      // uint2 index within 80 B row
    const bool active = (g < 6);
    float4 acc = make_float4(0.f, 0.f, 0.f, 0.f);
    for (int e = beg; e < end; e += 18) {
        const int rem = end - e;
        int s[3];
        float m[3];
#pragma unroll
        for (int q = 0; q < 3; ++q) {
            int slot = q * 6 + g;
            bool v = active && (slot < rem);
            int idx = v ? (e + slot) : beg;
            s[q] = esrc[idx];
            m[q] = v ? 1.f : 0.f;
        }
        uint2 u[3];
#pragma unroll
        for (int q = 0; q < 3; ++q)
            u[q] = ((const uint2*)(hwb + (size_t)s[q] * NC))[j];
#pragma unroll
        for (int q = 0; q < 3; ++q) {
            acc.x += bflo(u[q].x) * m[q];
            acc.y += bfhi(u[q].x) * m[q];
            acc.z += bflo(u[q].y) * m[q];
            acc.w += bfhi(u[q].y) * m[q];
        }
    }
    float4 tot = acc;
#pragma unroll
    for (int k = 1; k < 6; ++k) {
        tot.x += __shfl(acc.x, j + 10 * k);
        tot.y += __shfl(acc.y, j + 10 * k);
        tot.z += __shfl(acc.z, j + 10 * k);
        tot.w += __shfl(acc.w, j + 10 * k);
    }
    if (lane < 10) {
        float dnv = dst_norm[node];
        float4 bb = ((const float4*)b2)[j];
        float4 o;
        o.x = tot.x * dnv + bb.x;
        o.y = tot.y * dnv + bb.y;
        o.z = tot.z * dnv + bb.z;
        o.w = tot.w * dnv + bb.w;
        ((float4*)(out + (size_t)node * NC))[j] = o;
    }
}

extern "C" void kernel_launch(void* const* d_in, const int* in_sizes, int n_in,
                              void* d_out, int out_size, void* d_ws, size_t ws_size,
                              hipStream_t stream) {
    const float* x   = (const float*)d_in[0];
    const float* W1  = (const float*)d_in[1];
    const float* b1  = (const float*)d_in[2];
    const float* W2  = (const float*)d_in[3];
    const float* b2  = (const float*)d_in[4];
    const int*   src = (const int*)d_in[5];
    const int*   dst = (const int*)d_in[6];
    float* out = (float*)d_out;

    // workspace (4B units):
    // srcn[NN] | curDg[256] | curSg[256] | row_beg[NN] | row_end[NN] |
    // dstn[NN] | esrc[NBK*CAPB] | pad | xh[NN*64] | w1t[8192] | w2t[3072] |
    // hwb[NN*20]
    float* srcn = (float*)d_ws;
    int* curDg = (int*)(srcn + NN);
    int* curSg = curDg + 256;
    int* row_beg = curSg + 256;
    int* row_end = row_beg + NN;
    float* dstn  = (float*)(row_end + NN);
    int* esrc    = (int*)(dstn + NN);
    size_t ofs = (size_t)NN + 512 + 3 * (size_t)NN + (size_t)NBK * CAPB;
    ofs = (ofs + 3) & ~(size_t)3;                 // 16B align
    unsigned short* xh   = (unsigned short*)((float*)d_ws + ofs);
    unsigned short* w1t  = xh + (size_t)NN * INF;
    unsigned short* w2t  = w1t + 128 * 128;
    unsigned short* hwb  = w2t + 48 * 128;

    // edge-record scratch in d_out (12 MB of 16 MB) — dead before gather2 writes
    int* epartsD = (int*)d_out;                                 // 8.03 MB
    unsigned short* epartsS = (unsigned short*)(epartsD + (size_t)NBK * CAPB);  // 4.01 MB

    hipMemsetAsync(curDg, 0, 512 * sizeof(int), stream);   // curDg | curSg

    partconv_kernel<<<PBLK + CVB + 2, 256, 0, stream>>>(src, dst, curDg, curSg,
                                                        epartsD, epartsS,
                                                        x, xh, W1, W2, w1t, w2t);
    pass2_kernel<<<NBK, 512, 0, stream>>>(epartsD, epartsS, curDg, curSg,
                                          row_beg, row_end, esrc, srcn, dstn);
    fused_kernel<<<(NN + 31) / 32, 256, 0, stream>>>(row_beg, row_end, esrc, xh,
                                                     srcn, w1t, w2t, b1, dstn, hwb);
    gather2_kernel<<<(NN * 64 + 255) / 256, 256, 0, stream>>>(row_beg, row_end,
                                                              esrc, hwb,
                                                              dstn, b2, out);
}

// Round 12
// 275.250 us; speedup vs baseline: 1.1719x; 1.0112x over previous
//
#include <hip/hip_runtime.h>

// GCN: 2-layer GraphConv, N=100000, E=1600000, 128 -> 128 -> 40 (fp32).
// Round 21: R20 + two local fixes.
//   fused: At LDS stride 128->136 shorts (272B rows, banks rotate by 4/row)
//          — kills the 16-row same-bank ds_read_b128 conflict (2.5M cycles).
//   hwb:   rows padded 40->64 cols (exactly 2 cache lines). gather2 now uses
//          all 64 lanes: 8 edge slots x 8 lanes x uint4; pad cols only ever
//          land in discarded lanes (j>=5), so they need not be zeroed.
//   partconv/pass2: unchanged from R20 (fixed-capacity buckets).
constexpr int NN   = 100000;
constexpr int NE   = 1600000;
constexpr int INF  = 128;
constexpr int NC   = 40;
constexpr int HPAD = 64;                       // hwb padded row (bf16)

constexpr int BKSH = 9;                        // 512 nodes per coarse bucket
constexpr int NBK  = (NN + 511) / 512;         // 196 buckets
constexpr int CAPB = 10240;                    // fixed records per bucket
constexpr int EPB  = 4096;                     // edges per partition block
constexpr int PBLK = (NE + EPB - 1) / EPB;     // 391
constexpr int CVB  = 6250;                     // convert blocks (NN*128/8 / 256)
constexpr int ATS  = 136;                      // At LDS row stride (shorts)

typedef __attribute__((ext_vector_type(8))) short short8;
typedef __attribute__((ext_vector_type(4))) float f32x4;

__device__ __forceinline__ float bflo(unsigned int u) { return __uint_as_float(u << 16); }
__device__ __forceinline__ float bfhi(unsigned int u) { return __uint_as_float(u & 0xffff0000u); }
__device__ __forceinline__ unsigned short f2bf(float f) {          // RNE
    unsigned int u = __float_as_uint(f);
    return (unsigned short)((u + 0x7fffu + ((u >> 16) & 1u)) >> 16);
}
__device__ __forceinline__ unsigned int pack2(float a, float b) {
    return (unsigned int)f2bf(a) | ((unsigned int)f2bf(b) << 16);
}

// blocks 0..PBLK-1: dual partition into fixed-capacity buckets.
// blocks PBLK..PBLK+CVB-1: x (fp32) -> xh (bf16).
// last two blocks: W1 / W2 transpose -> bf16.
__global__ __launch_bounds__(256) void partconv_kernel(const int* __restrict__ src,
                                                       const int* __restrict__ dst,
                                                       int* __restrict__ curD_g,
                                                       int* __restrict__ curS_g,
                                                       int* __restrict__ epartsD,
                                                       unsigned short* __restrict__ epartsS,
                                                       const float* __restrict__ x,
                                                       unsigned short* __restrict__ xh,
                                                       const float* __restrict__ W1,
                                                       const float* __restrict__ W2,
                                                       unsigned short* __restrict__ w1t,
                                                       unsigned short* __restrict__ w2t) {
    const int tid = threadIdx.x;
    if (blockIdx.x >= PBLK) {
        int cb = blockIdx.x - PBLK;
        if (cb < CVB) {                          // ---- x convert ----
            int j = cb * 256 + tid;              // uint4 index, N*128/8 = 1.6M
            float4 v0 = ((const float4*)x)[2 * j];
            float4 v1 = ((const float4*)x)[2 * j + 1];
            uint4 o;
            o.x = pack2(v0.x, v0.y);
            o.y = pack2(v0.z, v0.w);
            o.z = pack2(v1.x, v1.y);
            o.w = pack2(v1.z, v1.w);
            ((uint4*)xh)[j] = o;
        } else if (cb == CVB) {                  // ---- W1 transpose ----
            for (int i = tid; i < 128 * 128; i += 256) {
                int k = i >> 7, n = i & 127;
                w1t[n * 128 + k] = f2bf(W1[i]);
            }
        } else {                                 // ---- W2 transpose ----
            for (int i = tid; i < 48 * 128; i += 256) {
                int n = i >> 7, k = i & 127;
                w2t[i] = f2bf((n < NC) ? W2[k * NC + n] : 0.f);
            }
        }
        return;
    }
    // ---- partition part ----
    __shared__ int sc[256];
    __shared__ int cntD[NBK], gadjD[NBK], curD[NBK];
    __shared__ int cntS[NBK], gadjS[NBK], curS[NBK];
    __shared__ int stageD[EPB];
    __shared__ unsigned short stageS[EPB];
    __shared__ unsigned char bidD[EPB];
    __shared__ unsigned char bidS[EPB];
    const int e0 = blockIdx.x * EPB;
    const int total = min(EPB, NE - e0);

    for (int i = tid; i < NBK; i += 256) { cntD[i] = 0; cntS[i] = 0; }
    __syncthreads();
    // phase A: count per bucket (both keys)
    for (int i = tid; i < total; i += 256) {
        atomicAdd(&cntD[dst[e0 + i] >> BKSH], 1);
        atomicAdd(&cntS[src[e0 + i] >> BKSH], 1);
    }
    __syncthreads();
    // exclusive scans of cntD, cntS; reserve global ranges (base = b*CAPB)
    {
        int v = (tid < NBK) ? cntD[tid] : 0;
        sc[tid] = v;
        __syncthreads();
        for (int off = 1; off < 256; off <<= 1) {
            int t = (tid >= off) ? sc[tid - off] : 0;
            __syncthreads();
            sc[tid] += t;
            __syncthreads();
        }
        if (tid < NBK) {
            int excl = sc[tid] - v;
            curD[tid] = excl;
            int g = (v > 0) ? atomicAdd(&curD_g[tid], v) : 0;
            gadjD[tid] = tid * CAPB + g - excl;
        }
        __syncthreads();
        v = (tid < NBK) ? cntS[tid] : 0;
        sc[tid] = v;
        __syncthreads();
        for (int off = 1; off < 256; off <<= 1) {
            int t = (tid >= off) ? sc[tid - off] : 0;
            __syncthreads();
            sc[tid] += t;
            __syncthreads();
        }
        if (tid < NBK) {
            int excl = sc[tid] - v;
            curS[tid] = excl;
            int g = (v > 0) ? atomicAdd(&curS_g[tid], v) : 0;
            gadjS[tid] = tid * CAPB + g - excl;
        }
    }
    __syncthreads();
    // phase B: re-read edges, stage grouped by bucket (both keys)
    for (int i = tid; i < total; i += 256) {
        int s = src[e0 + i];
        int d = dst[e0 + i];
        int bD = d >> BKSH;
        int offD = atomicAdd(&curD[bD], 1);
        stageD[offD] = s | ((d - (bD << BKSH)) << 17);
        bidD[offD] = (unsigned char)bD;
        int bS = s >> BKSH;
        int offS = atomicAdd(&curS[bS], 1);
        stageS[offS] = (unsigned short)(s - (bS << BKSH));
        bidS[offS] = (unsigned char)bS;
    }
    __syncthreads();
    // dumps: consecutive j within a bucket-run -> consecutive global addresses
    for (int j = tid; j < total; j += 256) {
        int b = bidD[j];
        epartsD[gadjD[b] + j] = stageD[j];
    }
    for (int j = tid; j < total; j += 256) {
        int b = bidS[j];
        epartsS[gadjS[b] + j] = stageS[j];
    }
}

// per-bucket: dst CSR (hist+scan+LDS scatter -> row_beg/row_end, dstn, esrc)
// AND src out-degree hist -> srcn. Bases are b*CAPB; counts from cursors.
__global__ __launch_bounds__(512) void pass2_kernel(const int* __restrict__ epartsD,
                                                    const unsigned short* __restrict__ epartsS,
                                                    const int* __restrict__ curD_g,
                                                    const int* __restrict__ curS_g,
                                                    int* __restrict__ row_beg,
                                                    int* __restrict__ row_end,
                                                    int* __restrict__ esrc,
                                                    float* __restrict__ srcn,
                                                    float* __restrict__ dstn) {
    __shared__ int hist[512];
    __shared__ int cur[512];
    __shared__ int histS[512];
    __shared__ int lesrc[CAPB];
    const int tid = threadIdx.x;
    const int b = blockIdx.x;

    const int base  = b * CAPB;
    const int cnt   = curD_g[b];
    const int cntS  = curS_g[b];
    const int n0 = b << BKSH;
    const int nloc = min(512, NN - n0);

    hist[tid] = 0;
    histS[tid] = 0;
    __syncthreads();
    for (int j = tid; j < cnt; j += 512)
        atomicAdd(&hist[epartsD[base + j] >> 17], 1);
    for (int j = tid; j < cntS; j += 512)
        atomicAdd(&histS[(int)epartsS[base + j]], 1);
    __syncthreads();
    int myc = hist[tid];
    int mycS = histS[tid];
    for (int off = 1; off < 512; off <<= 1) {
        int t = (tid >= off) ? hist[tid - off] : 0;
        __syncthreads();
        hist[tid] += t;
        __syncthreads();
    }
    int excl = hist[tid] - myc;
    cur[tid] = excl;
    if (tid < nloc) {
        int g = n0 + tid;
        row_beg[g] = base + excl;
        row_end[g] = base + excl + myc;
        dstn[g] = rsqrtf(fmaxf((float)myc, 1.0f));    // dst_norm (in-degree)
        srcn[g] = rsqrtf(fmaxf((float)mycS, 1.0f));   // src_norm (out-degree)
    }
    __syncthreads();
    for (int j = tid; j < cnt; j += 512) {
        int rec = epartsD[base + j];
        int pos = atomicAdd(&cur[rec >> 17], 1);
        lesrc[pos] = rec & 0x1FFFF;
    }
    __syncthreads();
    for (int j = tid; j < cnt; j += 512) esrc[base + j] = lesrc[j];
}

// Fused gather1 + GEMM1 + GEMM2. 32 nodes/block, 4 waves x 8 nodes serial
// (single-stream gather body, 28 VGPR), (256,8), 3125 blocks.
// At stride 136 shorts (272B rows): banks rotate 4/row -> no 16-row conflict.
// GEMM1 split (row-tile, nt-half) = (wv>>1, wv&1); race-safe barriers.
// hwb written at stride HPAD=64 (pad cols 40-63 left unwritten — only ever
// read into discarded lanes in gather2).
__global__ __launch_bounds__(256, 8) void fused_kernel(const int* __restrict__ row_beg,
                                                       const int* __restrict__ row_end,
                                                       const int* __restrict__ esrc,
                                                       const unsigned short* __restrict__ xh,
                                                       const float* __restrict__ srcn,
                                                       const unsigned short* __restrict__ w1t,
                                                       const unsigned short* __restrict__ w2t,
                                                       const float* __restrict__ b1,
                                                       const float* __restrict__ dstn,
                                                       unsigned short* __restrict__ hwb) {
    __shared__ unsigned short At[32 * ATS];    // 8.5 KB: agg tile, then h tile
    __shared__ float dn[32], sn[32], b1l[128];
    const int tid  = threadIdx.x;
    const int r0   = blockIdx.x * 32;
    const int wv   = tid >> 6;
    const int lane = tid & 63;

    if (tid < 32) {
        int r = r0 + tid;
        dn[tid] = (r < NN) ? dstn[r] : 0.f;
        sn[tid] = (r < NN) ? srcn[r] : 0.f;
    }
    if (tid >= 64 && tid < 192) b1l[tid - 64] = b1[tid - 64];
    __syncthreads();

    // ---- phase 1: gather 8 nodes serially (single-stream body) ----
    const int quad = lane >> 4;       // edge-slot group 0..3
    const int l16  = lane & 15;       // uint4 index within 256 B row
    for (int i = 0; i < 8; ++i) {
        const int node = r0 + wv * 8 + i;
        float a0 = 0.f, a1 = 0.f, a2 = 0.f, a3 = 0.f;
        float a4 = 0.f, a5 = 0.f, a6 = 0.f, a7 = 0.f;
        if (node < NN) {
            int beg = __builtin_amdgcn_readfirstlane(row_beg[node]);
            int end = __builtin_amdgcn_readfirstlane(row_end[node]);
            for (int e = beg; e < end; e += 16) {
                const int rem = end - e;
                int s[4];
#pragma unroll
                for (int t = 0; t < 4; ++t) {
                    int slot = t * 4 + quad;
                    s[t] = esrc[(slot < rem) ? (e + slot) : beg];
                }
                float n[4];
                uint4 u[4];
#pragma unroll
                for (int t = 0; t < 4; ++t) {
                    int slot = t * 4 + quad;
                    n[t] = (slot < rem) ? srcn[s[t]] : 0.f;
                    u[t] = ((const uint4*)(xh + (size_t)s[t] * INF))[l16];
                }
#pragma unroll
                for (int t = 0; t < 4; ++t) {
                    a0 += bflo(u[t].x) * n[t]; a1 += bfhi(u[t].x) * n[t];
                    a2 += bflo(u[t].y) * n[t]; a3 += bfhi(u[t].y) * n[t];
                    a4 += bflo(u[t].z) * n[t]; a5 += bfhi(u[t].z) * n[t];
                    a6 += bflo(u[t].w) * n[t]; a7 += bfhi(u[t].w) * n[t];
                }
            }
        }
        a0 += __shfl_down(a0, 32); a1 += __shfl_down(a1, 32);
        a2 += __shfl_down(a2, 32); a3 += __shfl_down(a3, 32);
        a4 += __shfl_down(a4, 32); a5 += __shfl_down(a5, 32);
        a6 += __shfl_down(a6, 32); a7 += __shfl_down(a7, 32);
        a0 += __shfl_down(a0, 16); a1 += __shfl_down(a1, 16);
        a2 += __shfl_down(a2, 16); a3 += __shfl_down(a3, 16);
        a4 += __shfl_down(a4, 16); a5 += __shfl_down(a5, 16);
        a6 += __shfl_down(a6, 16); a7 += __shfl_down(a7, 16);
        if (lane < 16) {
            uint4 o;
            o.x = pack2(a0, a1);
            o.y = pack2(a2, a3);
            o.z = pack2(a4, a5);
            o.w = pack2(a6, a7);
            *(uint4*)&At[(wv * 8 + i) * ATS + l16 * 8] = o;
        }
    }
    __syncthreads();   // cross-wave: GEMM reads rows gathered by other waves

    // ---- phase 2: MFMA GEMM1 (+relu), split (row-tile, nt-half) ----
    const int lrow  = lane & 15;
    const int lquad = lane >> 4;
    const int rt    = wv >> 1;            // row-tile 0 (rows 0-15) / 1 (16-31)
    const int ntB   = (wv & 1) * 4;       // nt-half 0-3 / 4-7

    // ALL waves snapshot their A-frags to registers before ANY h write.
    short8 afrag[4];
#pragma unroll
    for (int ks = 0; ks < 4; ++ks)
        afrag[ks] = *(const short8*)&At[(rt * 16 + lrow) * ATS + ks * 32 + lquad * 8];
    __syncthreads();   // agg reads complete before h overwrites At

    float hreg[4][4];
#pragma unroll
    for (int nt2 = 0; nt2 < 4; ++nt2) {
        f32x4 acc = {0.f, 0.f, 0.f, 0.f};
#pragma unroll
        for (int ks = 0; ks < 4; ++ks) {
            short8 bfr = *(const short8*)&w1t[((ntB + nt2) * 16 + lrow) * 128 + ks * 32 + lquad * 8];
            acc = __builtin_amdgcn_mfma_f32_16x16x32_bf16(afrag[ks], bfr, acc, 0, 0, 0);
        }
#pragma unroll
        for (int i = 0; i < 4; ++i) hreg[nt2][i] = acc[i];
    }
#pragma unroll
    for (int nt2 = 0; nt2 < 4; ++nt2) {
        int col = (ntB + nt2) * 16 + lrow;
        float bb = b1l[col];
#pragma unroll
        for (int i = 0; i < 4; ++i) {
            int row = rt * 16 + lquad * 4 + i;
            At[row * ATS + col] = f2bf(fmaxf(hreg[nt2][i] * dn[row] + bb, 0.f));
        }
    }
    __syncthreads();   // cross-wave: GEMM2 reads h cols written by nt-half peer

    // ---- GEMM2 on waves 0/2 (row-tile wv>>1) ----
    if ((wv & 1) == 0) {
        short8 hf[4];
#pragma unroll
        for (int ks = 0; ks < 4; ++ks)
            hf[ks] = *(const short8*)&At[(rt * 16 + lrow) * ATS + ks * 32 + lquad * 8];
#pragma unroll
        for (int nt = 0; nt < 3; ++nt) {
            f32x4 acc = {0.f, 0.f, 0.f, 0.f};
#pragma unroll
            for (int ks = 0; ks < 4; ++ks) {
                short8 bfr = *(const short8*)&w2t[(nt * 16 + lrow) * 128 + ks * 32 + lquad * 8];
                acc = __builtin_amdgcn_mfma_f32_16x16x32_bf16(hf[ks], bfr, acc, 0, 0, 0);
            }
            int col = nt * 16 + lrow;
            if (col < NC) {
#pragma unroll
                for (int i = 0; i < 4; ++i) {
                    int row = rt * 16 + lquad * 4 + i;
                    int grow = r0 + row;
                    if (grow < NN)
                        hwb[(size_t)grow * HPAD + col] = f2bf(acc[i] * sn[row]);
                }
            }
        }
    }
}

// one wave per node, hwb rows padded to 128 B. lane = g*8+j (g<8, j<8):
// 8 edge slots per step, each row read by 8 lanes as uint4 (8 bf16).
// Predicated 24-edge batches (3 loads/lane in flight); invalid slots clamp
// to edge `beg` with multiplicative zero mask. Pad cols (40-63) land only in
// lanes j>=5, which never store. fp32 acc; 3-round shfl reduce into g==0
// lanes; lanes j<5 store 8 cols each with fused *dstn + b2.
__global__ __launch_bounds__(256) void gather2_kernel(const int* __restrict__ row_beg,
                                                      const int* __restrict__ row_end,
                                                      const int* __restrict__ esrc,
                                                      const unsigned short* __restrict__ hwb,
                                                      const float* __restrict__ dst_norm,
                                                      const float* __restrict__ b2,
                                                      float* __restrict__ out) {
    int node = (blockIdx.x * blockDim.x + threadIdx.x) >> 6;
    int lane = threadIdx.x & 63;
    if (node >= NN) return;
    int beg = __builtin_amdgcn_readfirstlane(row_beg[node]);
    int end = __builtin_amdgcn_readfirstlane(row_end[node]);
    const int g = lane >> 3;          // edge slot 0..7
    const int j = lane & 7;           // uint4 index within 128 B row
    float a0 = 0.f, a1 = 0.f, a2 = 0.f, a3 = 0.f;
    float a4 = 0.f, a5 = 0.f, a6 = 0.f, a7 = 0.f;
    for (int e = beg; e < end; e += 24) {
        const int rem = end - e;
        int s[3];
        float m[3];
#pragma unroll
        for (int q = 0; q < 3; ++q) {
            int slot = q * 8 + g;
            bool v = (slot < rem);
            s[q] = esrc[v ? (e + slot) : beg];
            m[q] = v ? 1.f : 0.f;
        }
        uint4 u[3];
#pragma unroll
        for (int q = 0; q < 3; ++q)
            u[q] = ((const uint4*)(hwb + (size_t)s[q] * HPAD))[j];
#pragma unroll
        for (int q = 0; q < 3; ++q) {
            a0 += bflo(u[q].x) * m[q]; a1 += bfhi(u[q].x) * m[q];
            a2 += bflo(u[q].y) * m[q]; a3 += bfhi(u[q].y) * m[q];
            a4 += bflo(u[q].z) * m[q]; a5 += bfhi(u[q].z) * m[q];
            a6 += bflo(u[q].w) * m[q]; a7 += bfhi(u[q].w) * m[q];
        }
    }
    // reduce over the 8 g-groups (same j): lanes l <- l+32, l+16, l+8
    a0 += __shfl_down(a0, 32); a1 += __shfl_down(a1, 32);
    a2 += __shfl_down(a2, 32); a3 += __shfl_down(a3, 32);
    a4 += __shfl_down(a4, 32); a5 += __shfl_down(a5, 32);
    a6 += __shfl_down(a6, 32); a7 += __shfl_down(a7, 32);
    a0 += __shfl_down(a0, 16); a1 += __shfl_down(a1, 16);
    a2 += __shfl_down(a2, 16); a3 += __shfl_down(a3, 16);
    a4 += __shfl_down(a4, 16); a5 += __shfl_down(a5, 16);
    a6 += __shfl_down(a6, 16); a7 += __shfl_down(a7, 16);
    a0 += __shfl_down(a0, 8);  a1 += __shfl_down(a1, 8);
    a2 += __shfl_down(a2, 8);  a3 += __shfl_down(a3, 8);
    a4 += __shfl_down(a4, 8);  a5 += __shfl_down(a5, 8);
    a6 += __shfl_down(a6, 8);  a7 += __shfl_down(a7, 8);
    if (lane < 5) {                    // j = lane, g == 0: cols 8j..8j+7
        float dnv = dst_norm[node];
        float4 bb0 = ((const float4*)b2)[2 * lane];
        float4 bb1 = ((const float4*)b2)[2 * lane + 1];
        float4 o0, o1;
        o0.x = a0 * dnv + bb0.x;
        o0.y = a1 * dnv + bb0.y;
        o0.z = a2 * dnv + bb0.z;
        o0.w = a3 * dnv + bb0.w;
        o1.x = a4 * dnv + bb1.x;
        o1.y = a5 * dnv + bb1.y;
        o1.z = a6 * dnv + bb1.z;
        o1.w = a7 * dnv + bb1.w;
        float4* op = (float4*)(out + (size_t)node * NC);
        op[2 * lane]     = o0;
        op[2 * lane + 1] = o1;
    }
}

extern "C" void kernel_launch(void* const* d_in, const int* in_sizes, int n_in,
                              void* d_out, int out_size, void* d_ws, size_t ws_size,
                              hipStream_t stream) {
    const float* x   = (const float*)d_in[0];
    const float* W1  = (const float*)d_in[1];
    const float* b1  = (const float*)d_in[2];
    const float* W2  = (const float*)d_in[3];
    const float* b2  = (const float*)d_in[4];
    const int*   src = (const int*)d_in[5];
    const int*   dst = (const int*)d_in[6];
    float* out = (float*)d_out;

    // workspace (4B units):
    // srcn[NN] | curDg[256] | curSg[256] | row_beg[NN] | row_end[NN] |
    // dstn[NN] | esrc[NBK*CAPB] | pad | xh[NN*64] | w1t[8192] | w2t[3072] |
    // hwb[NN*32]  (bf16 NN x 64)
    float* srcn = (float*)d_ws;
    int* curDg = (int*)(srcn + NN);
    int* curSg = curDg + 256;
    int* row_beg = curSg + 256;
    int* row_end = row_beg + NN;
    float* dstn  = (float*)(row_end + NN);
    int* esrc    = (int*)(dstn + NN);
    size_t ofs = (size_t)NN + 512 + 3 * (size_t)NN + (size_t)NBK * CAPB;
    ofs = (ofs + 3) & ~(size_t)3;                 // 16B align
    unsigned short* xh   = (unsigned short*)((float*)d_ws + ofs);
    unsigned short* w1t  = xh + (size_t)NN * INF;
    unsigned short* w2t  = w1t + 128 * 128;
    unsigned short* hwb  = w2t + 48 * 128;

    // edge-record scratch in d_out (12 MB of 16 MB) — dead before gather2 writes
    int* epartsD = (int*)d_out;                                 // 8.03 MB
    unsigned short* epartsS = (unsigned short*)(epartsD + (size_t)NBK * CAPB);  // 4.01 MB

    hipMemsetAsync(curDg, 0, 512 * sizeof(int), stream);   // curDg | curSg

    partconv_kernel<<<PBLK + CVB + 2, 256, 0, stream>>>(src, dst, curDg, curSg,
                                                        epartsD, epartsS,
                                                        x, xh, W1, W2, w1t, w2t);
    pass2_kernel<<<NBK, 512, 0, stream>>>(epartsD, epartsS, curDg, curSg,
                                          row_beg, row_end, esrc, srcn, dstn);
    fused_kernel<<<(NN + 31) / 32, 256, 0, stream>>>(row_beg, row_end, esrc, xh,
                                                     srcn, w1t, w2t, b1, dstn, hwb);
    gather2_kernel<<<(NN * 64 + 255) / 256, 256, 0, stream>>>(row_beg, row_end,
                                                              esrc, hwb,
                                                              dstn, b2, out);
}

// Round 13
// 272.803 us; speedup vs baseline: 1.1824x; 1.0090x over previous
//
#include <hip/hip_runtime.h>

// GCN: 2-layer GraphConv, N=100000, E=1600000, 128 -> 128 -> 40 (fp32).
// Round 22: R21 + hidden-kernel parallelism.
//   pass2:   1024 threads/block (was 512) — 196 blocks was 0.76 blocks/CU,
//            record loops (hist/scatter/dump) now 2x parallel; scan stays
//            512-wide with uniform barriers.
//   gather2: 32 edges in flight (4 predicated batches of 8; was 3).
//   partconv/fused: unchanged from R21.
constexpr int NN   = 100000;
constexpr int NE   = 1600000;
constexpr int INF  = 128;
constexpr int NC   = 40;
constexpr int HPAD = 64;                       // hwb padded row (bf16)

constexpr int BKSH = 9;                        // 512 nodes per coarse bucket
constexpr int NBK  = (NN + 511) / 512;         // 196 buckets
constexpr int CAPB = 10240;                    // fixed records per bucket
constexpr int EPB  = 4096;                     // edges per partition block
constexpr int PBLK = (NE + EPB - 1) / EPB;     // 391
constexpr int CVB  = 6250;                     // convert blocks (NN*128/8 / 256)
constexpr int ATS  = 136;                      // At LDS row stride (shorts)

typedef __attribute__((ext_vector_type(8))) short short8;
typedef __attribute__((ext_vector_type(4))) float f32x4;

__device__ __forceinline__ float bflo(unsigned int u) { return __uint_as_float(u << 16); }
__device__ __forceinline__ float bfhi(unsigned int u) { return __uint_as_float(u & 0xffff0000u); }
__device__ __forceinline__ unsigned short f2bf(float f) {          // RNE
    unsigned int u = __float_as_uint(f);
    return (unsigned short)((u + 0x7fffu + ((u >> 16) & 1u)) >> 16);
}
__device__ __forceinline__ unsigned int pack2(float a, float b) {
    return (unsigned int)f2bf(a) | ((unsigned int)f2bf(b) << 16);
}

// blocks 0..PBLK-1: dual partition into fixed-capacity buckets.
// blocks PBLK..PBLK+CVB-1: x (fp32) -> xh (bf16).
// last two blocks: W1 / W2 transpose -> bf16.
__global__ __launch_bounds__(256) void partconv_kernel(const int* __restrict__ src,
                                                       const int* __restrict__ dst,
                                                       int* __restrict__ curD_g,
                                                       int* __restrict__ curS_g,
                                                       int* __restrict__ epartsD,
                                                       unsigned short* __restrict__ epartsS,
                                                       const float* __restrict__ x,
                                                       unsigned short* __restrict__ xh,
                                                       const float* __restrict__ W1,
                                                       const float* __restrict__ W2,
                                                       unsigned short* __restrict__ w1t,
                                                       unsigned short* __restrict__ w2t) {
    const int tid = threadIdx.x;
    if (blockIdx.x >= PBLK) {
        int cb = blockIdx.x - PBLK;
        if (cb < CVB) {                          // ---- x convert ----
            int j = cb * 256 + tid;              // uint4 index, N*128/8 = 1.6M
            float4 v0 = ((const float4*)x)[2 * j];
            float4 v1 = ((const float4*)x)[2 * j + 1];
            uint4 o;
            o.x = pack2(v0.x, v0.y);
            o.y = pack2(v0.z, v0.w);
            o.z = pack2(v1.x, v1.y);
            o.w = pack2(v1.z, v1.w);
            ((uint4*)xh)[j] = o;
        } else if (cb == CVB) {                  // ---- W1 transpose ----
            for (int i = tid; i < 128 * 128; i += 256) {
                int k = i >> 7, n = i & 127;
                w1t[n * 128 + k] = f2bf(W1[i]);
            }
        } else {                                 // ---- W2 transpose ----
            for (int i = tid; i < 48 * 128; i += 256) {
                int n = i >> 7, k = i & 127;
                w2t[i] = f2bf((n < NC) ? W2[k * NC + n] : 0.f);
            }
        }
        return;
    }
    // ---- partition part ----
    __shared__ int sc[256];
    __shared__ int cntD[NBK], gadjD[NBK], curD[NBK];
    __shared__ int cntS[NBK], gadjS[NBK], curS[NBK];
    __shared__ int stageD[EPB];
    __shared__ unsigned short stageS[EPB];
    __shared__ unsigned char bidD[EPB];
    __shared__ unsigned char bidS[EPB];
    const int e0 = blockIdx.x * EPB;
    const int total = min(EPB, NE - e0);

    for (int i = tid; i < NBK; i += 256) { cntD[i] = 0; cntS[i] = 0; }
    __syncthreads();
    // phase A: count per bucket (both keys)
    for (int i = tid; i < total; i += 256) {
        atomicAdd(&cntD[dst[e0 + i] >> BKSH], 1);
        atomicAdd(&cntS[src[e0 + i] >> BKSH], 1);
    }
    __syncthreads();
    // exclusive scans of cntD, cntS; reserve global ranges (base = b*CAPB)
    {
        int v = (tid < NBK) ? cntD[tid] : 0;
        sc[tid] = v;
        __syncthreads();
        for (int off = 1; off < 256; off <<= 1) {
            int t = (tid >= off) ? sc[tid - off] : 0;
            __syncthreads();
            sc[tid] += t;
            __syncthreads();
        }
        if (tid < NBK) {
            int excl = sc[tid] - v;
            curD[tid] = excl;
            int g = (v > 0) ? atomicAdd(&curD_g[tid], v) : 0;
            gadjD[tid] = tid * CAPB + g - excl;
        }
        __syncthreads();
        v = (tid < NBK) ? cntS[tid] : 0;
        sc[tid] = v;
        __syncthreads();
        for (int off = 1; off < 256; off <<= 1) {
            int t = (tid >= off) ? sc[tid - off] : 0;
            __syncthreads();
            sc[tid] += t;
            __syncthreads();
        }
        if (tid < NBK) {
            int excl = sc[tid] - v;
            curS[tid] = excl;
            int g = (v > 0) ? atomicAdd(&curS_g[tid], v) : 0;
            gadjS[tid] = tid * CAPB + g - excl;
        }
    }
    __syncthreads();
    // phase B: re-read edges, stage grouped by bucket (both keys)
    for (int i = tid; i < total; i += 256) {
        int s = src[e0 + i];
        int d = dst[e0 + i];
        int bD = d >> BKSH;
        int offD = atomicAdd(&curD[bD], 1);
        stageD[offD] = s | ((d - (bD << BKSH)) << 17);
        bidD[offD] = (unsigned char)bD;
        int bS = s >> BKSH;
        int offS = atomicAdd(&curS[bS], 1);
        stageS[offS] = (unsigned short)(s - (bS << BKSH));
        bidS[offS] = (unsigned char)bS;
    }
    __syncthreads();
    // dumps: consecutive j within a bucket-run -> consecutive global addresses
    for (int j = tid; j < total; j += 256) {
        int b = bidD[j];
        epartsD[gadjD[b] + j] = stageD[j];
    }
    for (int j = tid; j < total; j += 256) {
        int b = bidS[j];
        epartsS[gadjS[b] + j] = stageS[j];
    }
}

// per-bucket (1024 threads): dst CSR (hist+scan+LDS scatter -> row_beg/
// row_end, dstn, esrc) AND src out-degree hist -> srcn. Bases b*CAPB;
// counts from cursors. Scan is 512-wide; all threads execute barriers.
__global__ __launch_bounds__(1024) void pass2_kernel(const int* __restrict__ epartsD,
                                                     const unsigned short* __restrict__ epartsS,
                                                     const int* __restrict__ curD_g,
                                                     const int* __restrict__ curS_g,
                                                     int* __restrict__ row_beg,
                                                     int* __restrict__ row_end,
                                                     int* __restrict__ esrc,
                                                     float* __restrict__ srcn,
                                                     float* __restrict__ dstn) {
    __shared__ int hist[512];
    __shared__ int cur[512];
    __shared__ int histS[512];
    __shared__ int lesrc[CAPB];
    const int tid = threadIdx.x;
    const int b = blockIdx.x;

    const int base  = b * CAPB;
    const int cnt   = curD_g[b];
    const int cntS  = curS_g[b];
    const int n0 = b << BKSH;
    const int nloc = min(512, NN - n0);

    if (tid < 512) { hist[tid] = 0; histS[tid] = 0; }
    __syncthreads();
    for (int j = tid; j < cnt; j += 1024)
        atomicAdd(&hist[epartsD[base + j] >> 17], 1);
    for (int j = tid; j < cntS; j += 1024)
        atomicAdd(&histS[(int)epartsS[base + j]], 1);
    __syncthreads();
    int myc  = (tid < 512) ? hist[tid] : 0;
    int mycS = (tid < 512) ? histS[tid] : 0;
    for (int off = 1; off < 512; off <<= 1) {
        int t = (tid < 512 && tid >= off) ? hist[tid - off] : 0;
        __syncthreads();
        if (tid < 512) hist[tid] += t;
        __syncthreads();
    }
    if (tid < 512) {
        int excl = hist[tid] - myc;
        cur[tid] = excl;
        if (tid < nloc) {
            int g = n0 + tid;
            row_beg[g] = base + excl;
            row_end[g] = base + excl + myc;
            dstn[g] = rsqrtf(fmaxf((float)myc, 1.0f));    // dst_norm (in-degree)
            srcn[g] = rsqrtf(fmaxf((float)mycS, 1.0f));   // src_norm (out-degree)
        }
    }
    __syncthreads();
    for (int j = tid; j < cnt; j += 1024) {
        int rec = epartsD[base + j];
        int pos = atomicAdd(&cur[rec >> 17], 1);
        lesrc[pos] = rec & 0x1FFFF;
    }
    __syncthreads();
    for (int j = tid; j < cnt; j += 1024) esrc[base + j] = lesrc[j];
}

// Fused gather1 + GEMM1 + GEMM2. 32 nodes/block, 4 waves x 8 nodes serial
// (single-stream gather body, 28 VGPR), (256,8), 3125 blocks.
// At stride 136 shorts (272B rows): banks rotate 4/row -> no 16-row conflict.
// GEMM1 split (row-tile, nt-half) = (wv>>1, wv&1); race-safe barriers.
// hwb written at stride HPAD=64 (pad cols 40-63 left unwritten — only ever
// read into discarded lanes in gather2).
__global__ __launch_bounds__(256, 8) void fused_kernel(const int* __restrict__ row_beg,
                                                       const int* __restrict__ row_end,
                                                       const int* __restrict__ esrc,
                                                       const unsigned short* __restrict__ xh,
                                                       const float* __restrict__ srcn,
                                                       const unsigned short* __restrict__ w1t,
                                                       const unsigned short* __restrict__ w2t,
                                                       const float* __restrict__ b1,
                                                       const float* __restrict__ dstn,
                                                       unsigned short* __restrict__ hwb) {
    __shared__ unsigned short At[32 * ATS];    // 8.5 KB: agg tile, then h tile
    __shared__ float dn[32], sn[32], b1l[128];
    const int tid  = threadIdx.x;
    const int r0   = blockIdx.x * 32;
    const int wv   = tid >> 6;
    const int lane = tid & 63;

    if (tid < 32) {
        int r = r0 + tid;
        dn[tid] = (r < NN) ? dstn[r] : 0.f;
        sn[tid] = (r < NN) ? srcn[r] : 0.f;
    }
    if (tid >= 64 && tid < 192) b1l[tid - 64] = b1[tid - 64];
    __syncthreads();

    // ---- phase 1: gather 8 nodes serially (single-stream body) ----
    const int quad = lane >> 4;       // edge-slot group 0..3
    const int l16  = lane & 15;       // uint4 index within 256 B row
    for (int i = 0; i < 8; ++i) {
        const int node = r0 + wv * 8 + i;
        float a0 = 0.f, a1 = 0.f, a2 = 0.f, a3 = 0.f;
        float a4 = 0.f, a5 = 0.f, a6 = 0.f, a7 = 0.f;
        if (node < NN) {
            int beg = __builtin_amdgcn_readfirstlane(row_beg[node]);
            int end = __builtin_amdgcn_readfirstlane(row_end[node]);
            for (int e = beg; e < end; e += 16) {
                const int rem = end - e;
                int s[4];
#pragma unroll
                for (int t = 0; t < 4; ++t) {
                    int slot = t * 4 + quad;
                    s[t] = esrc[(slot < rem) ? (e + slot) : beg];
                }
                float n[4];
                uint4 u[4];
#pragma unroll
                for (int t = 0; t < 4; ++t) {
                    int slot = t * 4 + quad;
                    n[t] = (slot < rem) ? srcn[s[t]] : 0.f;
                    u[t] = ((const uint4*)(xh + (size_t)s[t] * INF))[l16];
                }
#pragma unroll
                for (int t = 0; t < 4; ++t) {
                    a0 += bflo(u[t].x) * n[t]; a1 += bfhi(u[t].x) * n[t];
                    a2 += bflo(u[t].y) * n[t]; a3 += bfhi(u[t].y) * n[t];
                    a4 += bflo(u[t].z) * n[t]; a5 += bfhi(u[t].z) * n[t];
                    a6 += bflo(u[t].w) * n[t]; a7 += bfhi(u[t].w) * n[t];
                }
            }
        }
        a0 += __shfl_down(a0, 32); a1 += __shfl_down(a1, 32);
        a2 += __shfl_down(a2, 32); a3 += __shfl_down(a3, 32);
        a4 += __shfl_down(a4, 32); a5 += __shfl_down(a5, 32);
        a6 += __shfl_down(a6, 32); a7 += __shfl_down(a7, 32);
        a0 += __shfl_down(a0, 16); a1 += __shfl_down(a1, 16);
        a2 += __shfl_down(a2, 16); a3 += __shfl_down(a3, 16);
        a4 += __shfl_down(a4, 16); a5 += __shfl_down(a5, 16);
        a6 += __shfl_down(a6, 16); a7 += __shfl_down(a7, 16);
        if (lane < 16) {
            uint4 o;
            o.x = pack2(a0, a1);
            o.y = pack2(a2, a3);
            o.z = pack2(a4, a5);
            o.w = pack2(a6, a7);
            *(uint4*)&At[(wv * 8 + i) * ATS + l16 * 8] = o;
        }
    }
    __syncthreads();   // cross-wave: GEMM reads rows gathered by other waves

    // ---- phase 2: MFMA GEMM1 (+relu), split (row-tile, nt-half) ----
    const int lrow  = lane & 15;
    const int lquad = lane >> 4;
    const int rt    = wv >> 1;            // row-tile 0 (rows 0-15) / 1 (16-31)
    const int ntB   = (wv & 1) * 4;       // nt-half 0-3 / 4-7

    // ALL waves snapshot their A-frags to registers before ANY h write.
    short8 afrag[4];
#pragma unroll
    for (int ks = 0; ks < 4; ++ks)
        afrag[ks] = *(const short8*)&At[(rt * 16 + lrow) * ATS + ks * 32 + lquad * 8];
    __syncthreads();   // agg reads complete before h overwrites At

    float hreg[4][4];
#pragma unroll
    for (int nt2 = 0; nt2 < 4; ++nt2) {
        f32x4 acc = {0.f, 0.f, 0.f, 0.f};
#pragma unroll
        for (int ks = 0; ks < 4; ++ks) {
            short8 bfr = *(const short8*)&w1t[((ntB + nt2) * 16 + lrow) * 128 + ks * 32 + lquad * 8];
            acc = __builtin_amdgcn_mfma_f32_16x16x32_bf16(afrag[ks], bfr, acc, 0, 0, 0);
        }
#pragma unroll
        for (int i = 0; i < 4; ++i) hreg[nt2][i] = acc[i];
    }
#pragma unroll
    for (int nt2 = 0; nt2 < 4; ++nt2) {
        int col = (ntB + nt2) * 16 + lrow;
        float bb = b1l[col];
#pragma unroll
        for (int i = 0; i < 4; ++i) {
            int row = rt * 16 + lquad * 4 + i;
            At[row * ATS + col] = f2bf(fmaxf(hreg[nt2][i] * dn[row] + bb, 0.f));
        }
    }
    __syncthreads();   // cross-wave: GEMM2 reads h cols written by nt-half peer

    // ---- GEMM2 on waves 0/2 (row-tile wv>>1) ----
    if ((wv & 1) == 0) {
        short8 hf[4];
#pragma unroll
        for (int ks = 0; ks < 4; ++ks)
            hf[ks] = *(const short8*)&At[(rt * 16 + lrow) * ATS + ks * 32 + lquad * 8];
#pragma unroll
        for (int nt = 0; nt < 3; ++nt) {
            f32x4 acc = {0.f, 0.f, 0.f, 0.f};
#pragma unroll
            for (int ks = 0; ks < 4; ++ks) {
                short8 bfr = *(const short8*)&w2t[(nt * 16 + lrow) * 128 + ks * 32 + lquad * 8];
                acc = __builtin_amdgcn_mfma_f32_16x16x32_bf16(hf[ks], bfr, acc, 0, 0, 0);
            }
            int col = nt * 16 + lrow;
            if (col < NC) {
#pragma unroll
                for (int i = 0; i < 4; ++i) {
                    int row = rt * 16 + lquad * 4 + i;
                    int grow = r0 + row;
                    if (grow < NN)
                        hwb[(size_t)grow * HPAD + col] = f2bf(acc[i] * sn[row]);
                }
            }
        }
    }
}

// one wave per node, hwb rows padded to 128 B. lane = g*8+j (g<8, j<8):
// 8 edge slots per step, each row read by 8 lanes as uint4 (8 bf16).
// Predicated 32-edge batches (4 loads/lane in flight); invalid slots clamp
// to edge `beg` with multiplicative zero mask. Pad cols (40-63) land only in
// lanes j>=5, which never store. fp32 acc; 3-round shfl reduce into g==0
// lanes; lanes j<5 store 8 cols each with fused *dstn + b2.
__global__ __launch_bounds__(256) void gather2_kernel(const int* __restrict__ row_beg,
                                                      const int* __restrict__ row_end,
                                                      const int* __restrict__ esrc,
                                                      const unsigned short* __restrict__ hwb,
                                                      const float* __restrict__ dst_norm,
                                                      const float* __restrict__ b2,
                                                      float* __restrict__ out) {
    int node = (blockIdx.x * blockDim.x + threadIdx.x) >> 6;
    int lane = threadIdx.x & 63;
    if (node >= NN) return;
    int beg = __builtin_amdgcn_readfirstlane(row_beg[node]);
    int end = __builtin_amdgcn_readfirstlane(row_end[node]);
    const int g = lane >> 3;          // edge slot 0..7
    const int j = lane & 7;           // uint4 index within 128 B row
    float a0 = 0.f, a1 = 0.f, a2 = 0.f, a3 = 0.f;
    float a4 = 0.f, a5 = 0.f, a6 = 0.f, a7 = 0.f;
    for (int e = beg; e < end; e += 32) {
        const int rem = end - e;
        int s[4];
        float m[4];
#pragma unroll
        for (int q = 0; q < 4; ++q) {
            int slot = q * 8 + g;
            bool v = (slot < rem);
            s[q] = esrc[v ? (e + slot) : beg];
            m[q] = v ? 1.f : 0.f;
        }
        uint4 u[4];
#pragma unroll
        for (int q = 0; q < 4; ++q)
            u[q] = ((const uint4*)(hwb + (size_t)s[q] * HPAD))[j];
#pragma unroll
        for (int q = 0; q < 4; ++q) {
            a0 += bflo(u[q].x) * m[q]; a1 += bfhi(u[q].x) * m[q];
            a2 += bflo(u[q].y) * m[q]; a3 += bfhi(u[q].y) * m[q];
            a4 += bflo(u[q].z) * m[q]; a5 += bfhi(u[q].z) * m[q];
            a6 += bflo(u[q].w) * m[q]; a7 += bfhi(u[q].w) * m[q];
        }
    }
    // reduce over the 8 g-groups (same j): lanes l <- l+32, l+16, l+8
    a0 += __shfl_down(a0, 32); a1 += __shfl_down(a1, 32);
    a2 += __shfl_down(a2, 32); a3 += __shfl_down(a3, 32);
    a4 += __shfl_down(a4, 32); a5 += __shfl_down(a5, 32);
    a6 += __shfl_down(a6, 32); a7 += __shfl_down(a7, 32);
    a0 += __shfl_down(a0, 16); a1 += __shfl_down(a1, 16);
    a2 += __shfl_down(a2, 16); a3 += __shfl_down(a3, 16);
    a4 += __shfl_down(a4, 16); a5 += __shfl_down(a5, 16);
    a6 += __shfl_down(a6, 16); a7 += __shfl_down(a7, 16);
    a0 += __shfl_down(a0, 8);  a1 += __shfl_down(a1, 8);
    a2 += __shfl_down(a2, 8);  a3 += __shfl_down(a3, 8);
    a4 += __shfl_down(a4, 8);  a5 += __shfl_down(a5, 8);
    a6 += __shfl_down(a6, 8);  a7 += __shfl_down(a7, 8);
    if (lane < 5) {                    // j = lane, g == 0: cols 8j..8j+7
        float dnv = dst_norm[node];
        float4 bb0 = ((const float4*)b2)[2 * lane];
        float4 bb1 = ((const float4*)b2)[2 * lane + 1];
        float4 o0, o1;
        o0.x = a0 * dnv + bb0.x;
        o0.y = a1 * dnv + bb0.y;
        o0.z = a2 * dnv + bb0.z;
        o0.w = a3 * dnv + bb0.w;
        o1.x = a4 * dnv + bb1.x;
        o1.y = a5 * dnv + bb1.y;
        o1.z = a6 * dnv + bb1.z;
        o1.w = a7 * dnv + bb1.w;
        float4* op = (float4*)(out + (size_t)node * NC);
        op[2 * lane]     = o0;
        op[2 * lane + 1] = o1;
    }
}

extern "C" void kernel_launch(void* const* d_in, const int* in_sizes, int n_in,
                              void* d_out, int out_size, void* d_ws, size_t ws_size,
                              hipStream_t stream) {
    const float* x   = (const float*)d_in[0];
    const float* W1  = (const float*)d_in[1];
    const float* b1  = (const float*)d_in[2];
    const float* W2  = (const float*)d_in[3];
    const float* b2  = (const float*)d_in[4];
    const int*   src = (const int*)d_in[5];
    const int*   dst = (const int*)d_in[6];
    float* out = (float*)d_out;

    // workspace (4B units):
    // srcn[NN] | curDg[256] | curSg[256] | row_beg[NN] | row_end[NN] |
    // dstn[NN] | esrc[NBK*CAPB] | pad | xh[NN*64] | w1t[8192] | w2t[3072] |
    // hwb[NN*32]  (bf16 NN x 64)
    float* srcn = (float*)d_ws;
    int* curDg = (int*)(srcn + NN);
    int* curSg = curDg + 256;
    int* row_beg = curSg + 256;
    int* row_end = row_beg + NN;
    float* dstn  = (float*)(row_end + NN);
    int* esrc    = (int*)(dstn + NN);
    size_t ofs = (size_t)NN + 512 + 3 * (size_t)NN + (size_t)NBK * CAPB;
    ofs = (ofs + 3) & ~(size_t)3;                 // 16B align
    unsigned short* xh   = (unsigned short*)((float*)d_ws + ofs);
    unsigned short* w1t  = xh + (size_t)NN * INF;
    unsigned short* w2t  = w1t + 128 * 128;
    unsigned short* hwb  = w2t + 48 * 128;

    // edge-record scratch in d_out (12 MB of 16 MB) — dead before gather2 writes
    int* epartsD = (int*)d_out;                                 // 8.03 MB
    unsigned short* epartsS = (unsigned short*)(epartsD + (size_t)NBK * CAPB);  // 4.01 MB

    hipMemsetAsync(curDg, 0, 512 * sizeof(int), stream);   // curDg | curSg

    partconv_kernel<<<PBLK + CVB + 2, 256, 0, stream>>>(src, dst, curDg, curSg,
                                                        epartsD, epartsS,
                                                        x, xh, W1, W2, w1t, w2t);
    pass2_kernel<<<NBK, 1024, 0, stream>>>(epartsD, epartsS, curDg, curSg,
                                           row_beg, row_end, esrc, srcn, dstn);
    fused_kernel<<<(NN + 31) / 32, 256, 0, stream>>>(row_beg, row_end, esrc, xh,
                                                     srcn, w1t, w2t, b1, dstn, hwb);
    gather2_kernel<<<(NN * 64 + 255) / 256, 256, 0, stream>>>(row_beg, row_end,
                                                              esrc, hwb,
                                                              dstn, b2, out);
}